// Round 1
// baseline (1839.126 us; speedup 1.0000x reference)
//
#include <hip/hip_runtime.h>
#include <math.h>

#define Bn 4
#define Cn 256
#define CIn 128
#define Hn 64
#define Wn 64
#define Nn 4096
#define Gn 8
#define CPGn 32
#define EPSc 1e-5f

// ---------------- conv3x3 + bias ----------------
// grid (4 co-blocks, 64 h, 4 b), block 256.
// Each block: one output row h, 64 output channels, all 64 w.
__global__ __launch_bounds__(256) void k_conv3x3(
    const float* __restrict__ x, const float* __restrict__ w3,
    const float* __restrict__ b3, float* __restrict__ out) {
  __shared__ float lx[32][3][68];   // padded rows, 16B-aligned
  const int t = threadIdx.x;
  const int cb = blockIdx.x, h = blockIdx.y, b = blockIdx.z;
  const int co = cb * 64 + (t >> 2);
  const int w4 = (t & 3) * 16;
  float acc[16];
#pragma unroll
  for (int k = 0; k < 16; ++k) acc[k] = 0.f;

  for (int cc = 0; cc < 8; ++cc) {     // 8 chunks of 32 input channels
    for (int i = t; i < 32 * 3 * 68; i += 256) {
      int ci = i / 204, rem = i % 204, dh = rem / 68, j = rem % 68;
      int hh = h + dh - 1, ww = j - 1;
      float v = 0.f;
      if (j < 66 && hh >= 0 && hh < Hn && ww >= 0 && ww < Wn)
        v = x[(((size_t)b * Cn + cc * 32 + ci) * Hn + hh) * Wn + ww];
      lx[ci][dh][j] = v;
    }
    __syncthreads();
    for (int ci = 0; ci < 32; ++ci) {
      const float* wp = w3 + ((size_t)co * Cn + cc * 32 + ci) * 9;
#pragma unroll
      for (int dh = 0; dh < 3; ++dh) {
        float rr[18];
#pragma unroll
        for (int j = 0; j < 18; ++j) rr[j] = lx[ci][dh][w4 + j];
        float w0 = wp[dh * 3 + 0], w1 = wp[dh * 3 + 1], w2 = wp[dh * 3 + 2];
#pragma unroll
        for (int k = 0; k < 16; ++k)
          acc[k] += w0 * rr[k] + w1 * rr[k + 1] + w2 * rr[k + 2];
      }
    }
    __syncthreads();
  }
  const float bias = b3[co];
  float* op = out + ((size_t)b * Cn + co) * Nn + h * Wn + w4;
#pragma unroll
  for (int k = 0; k < 16; ++k) op[k] = acc[k] + bias;
}

// ---------------- GroupNorm stats (2-stage, no atomics) ----------------
__global__ __launch_bounds__(256) void k_gn_part(
    const float* __restrict__ xin, float* __restrict__ part) {
  const int s = blockIdx.x, g = blockIdx.y, b = blockIdx.z;
  const int t = threadIdx.x;
  const float* p = xin + ((size_t)b * Cn + g * CPGn) * Nn + s * 8192;
  float sum = 0.f, ssq = 0.f;
  for (int i = t * 4; i < 8192; i += 1024) {
    float4 v = *(const float4*)(p + i);
    sum += v.x + v.y + v.z + v.w;
    ssq += v.x * v.x + v.y * v.y + v.z * v.z + v.w * v.w;
  }
  __shared__ float r1[256], r2[256];
  r1[t] = sum; r2[t] = ssq;
  __syncthreads();
  for (int st = 128; st > 0; st >>= 1) {
    if (t < st) { r1[t] += r1[t + st]; r2[t] += r2[t + st]; }
    __syncthreads();
  }
  if (t == 0) {
    size_t idx = ((size_t)(b * Gn + g) * 16 + s) * 2;
    part[idx] = r1[0];
    part[idx + 1] = r2[0];
  }
}

__global__ void k_gn_final(const float* __restrict__ part, float* __restrict__ stats) {
  const int t = threadIdx.x;
  if (t < Bn * Gn) {
    float s = 0.f, ss = 0.f;
    for (int j = 0; j < 16; ++j) {
      s += part[(t * 16 + j) * 2];
      ss += part[(t * 16 + j) * 2 + 1];
    }
    const float inv = 1.f / (float)(CPGn * Nn);
    float mean = s * inv;
    float var = ss * inv - mean * mean;
    stats[t * 2] = mean;
    stats[t * 2 + 1] = rsqrtf(var + EPSc);
  }
}

// ---------------- GN1 apply + ReLU ----------------
__global__ __launch_bounds__(256) void k_gn1_apply(
    const float* __restrict__ xr, const float* __restrict__ stats,
    const float* __restrict__ gw, const float* __restrict__ gb,
    float* __restrict__ xs) {
  size_t i = ((size_t)blockIdx.x * 256 + threadIdx.x) * 4;
  int c = (int)((i >> 12) & 255);
  int bg = (int)(i >> 20) * Gn + (c >> 5);
  float mean = stats[bg * 2], rstd = stats[bg * 2 + 1];
  float sc = gw[c] * rstd;
  float sb = gb[c] - mean * sc;
  float4 v = *(const float4*)(xr + i);
  v.x = fmaxf(v.x * sc + sb, 0.f);
  v.y = fmaxf(v.y * sc + sb, 0.f);
  v.z = fmaxf(v.z * sc + sb, 0.f);
  v.w = fmaxf(v.w * sc + sb, 0.f);
  *(float4*)(xs + i) = v;
}

// ---------------- tiled fp32 GEMM: out = W[M,K] @ X[K,Nn] + bias ----------------
// tile: 128 m x 64 n, 256 threads, each 8m x 4n.
__device__ __forceinline__ void gemm_tile(
    const float* __restrict__ Wm, const float* __restrict__ bias,
    const float* __restrict__ Xb, float* __restrict__ outb,
    const int K, const int mb, const int nb, const bool trans) {
  __shared__ float Xs[32][64];
  __shared__ float Ws[128][33];
  const int t = threadIdx.x;
  const int m0 = (t >> 4) * 8, n0 = (t & 15) * 4;
  float acc[8][4];
#pragma unroll
  for (int i = 0; i < 8; ++i)
#pragma unroll
    for (int j = 0; j < 4; ++j) acc[i][j] = 0.f;

  for (int k0 = 0; k0 < K; k0 += 32) {
    for (int i = t; i < 2048; i += 256)
      Xs[i >> 6][i & 63] = Xb[(size_t)(k0 + (i >> 6)) * Nn + nb * 64 + (i & 63)];
    for (int i = t; i < 4096; i += 256)
      Ws[i >> 5][i & 31] = Wm[(size_t)(mb * 128 + (i >> 5)) * K + k0 + (i & 31)];
    __syncthreads();
#pragma unroll 4
    for (int kk = 0; kk < 32; ++kk) {
      float4 xv = *(const float4*)&Xs[kk][n0];
#pragma unroll
      for (int i = 0; i < 8; ++i) {
        float wv = Ws[m0 + i][kk];
        acc[i][0] += wv * xv.x; acc[i][1] += wv * xv.y;
        acc[i][2] += wv * xv.z; acc[i][3] += wv * xv.w;
      }
    }
    __syncthreads();
  }
#pragma unroll
  for (int i = 0; i < 8; ++i) {
    float bv = bias[mb * 128 + m0 + i];
#pragma unroll
    for (int j = 0; j < 4; ++j) {
      float v = acc[i][j] + bv;
      if (trans)
        outb[(size_t)(nb * 64 + n0 + j) * CIn + mb * 128 + m0 + i] = v;
      else
        outb[(size_t)(mb * 128 + m0 + i) * Nn + nb * 64 + n0 + j] = v;
    }
  }
}

// three 1x1 projections: theta (trans), g (trans), phi (natural)
__global__ __launch_bounds__(256) void k_proj(
    const float* __restrict__ xs,
    const float* __restrict__ thw, const float* __restrict__ thb,
    const float* __restrict__ gw, const float* __restrict__ gb,
    const float* __restrict__ phw, const float* __restrict__ phb,
    float* __restrict__ theta_t, float* __restrict__ g_t, float* __restrict__ phi_) {
  const int nb = blockIdx.x, which = blockIdx.y, b = blockIdx.z;
  const float* Xb = xs + (size_t)b * Cn * Nn;
  const float* Wm; const float* bs; float* ob; bool tr;
  if (which == 0)      { Wm = thw; bs = thb; ob = theta_t + (size_t)b * Nn * CIn; tr = true; }
  else if (which == 1) { Wm = gw;  bs = gb;  ob = g_t     + (size_t)b * Nn * CIn; tr = true; }
  else                 { Wm = phw; bs = phb; ob = phi_    + (size_t)b * CIn * Nn; tr = false; }
  gemm_tile(Wm, bs, Xb, ob, Cn, 0, nb, tr);
}

// final 1x1: wy[256][N] = w_w[256][128] @ y[128][N] + w_b
__global__ __launch_bounds__(256) void k_wconv(
    const float* __restrict__ y, const float* __restrict__ ww,
    const float* __restrict__ wb, float* __restrict__ wy) {
  const int nb = blockIdx.x, mb = blockIdx.y, b = blockIdx.z;
  gemm_tile(ww, wb, y + (size_t)b * CIn * Nn, wy + (size_t)b * Cn * Nn, CIn, mb, nb, false);
}

// ---------------- flash attention (fp32) ----------------
// grid (128 row-blocks, 4 b), block 256. 32 rows/block, 128-wide m tiles,
// online softmax. thread tile: 4 rows x 4 cols (rg = t>>5, cg = t&31).
__global__ __launch_bounds__(256) void k_attn(
    const float* __restrict__ theta_t, const float* __restrict__ phi_,
    const float* __restrict__ g_t, float* __restrict__ y) {
  __shared__ float th[32][128];
  __shared__ float Ss[32][132];
  __shared__ float red[32][8];
  __shared__ float Mrow[32], Lrow[32], Arow[32];
  const int t = threadIdx.x;
  const int rb = blockIdx.x, b = blockIdx.y;
  const int n0 = rb * 32;
  const float* thp = theta_t + ((size_t)(b * Nn + n0)) * CIn;
  for (int i = t; i < 32 * 128; i += 256) th[i >> 7][i & 127] = thp[i];
  if (t < 32) { Mrow[t] = -3e38f; Lrow[t] = 0.f; }
  __syncthreads();

  const int rg = t >> 5;   // 0..7  (4 rows each)
  const int cg = t & 31;   // 0..31 (4 cols each)
  const int r4 = rg * 4;
  float yacc[4][4];
#pragma unroll
  for (int i = 0; i < 4; ++i)
#pragma unroll
    for (int j = 0; j < 4; ++j) yacc[i][j] = 0.f;

  for (int m0 = 0; m0 < Nn; m0 += 128) {
    // S tile = theta(32x128) @ phi(128x128)
    float s_[4][4];
#pragma unroll
    for (int i = 0; i < 4; ++i)
#pragma unroll
      for (int j = 0; j < 4; ++j) s_[i][j] = 0.f;
    const float* php = phi_ + (size_t)b * CIn * Nn + m0 + cg * 4;
#pragma unroll 2
    for (int c = 0; c < 128; ++c) {
      float4 pv = *(const float4*)php;
      php += Nn;
      float a0 = th[r4 + 0][c], a1 = th[r4 + 1][c];
      float a2 = th[r4 + 2][c], a3 = th[r4 + 3][c];
      s_[0][0] += a0 * pv.x; s_[0][1] += a0 * pv.y; s_[0][2] += a0 * pv.z; s_[0][3] += a0 * pv.w;
      s_[1][0] += a1 * pv.x; s_[1][1] += a1 * pv.y; s_[1][2] += a1 * pv.z; s_[1][3] += a1 * pv.w;
      s_[2][0] += a2 * pv.x; s_[2][1] += a2 * pv.y; s_[2][2] += a2 * pv.z; s_[2][3] += a2 * pv.w;
      s_[3][0] += a3 * pv.x; s_[3][1] += a3 * pv.y; s_[3][2] += a3 * pv.z; s_[3][3] += a3 * pv.w;
    }
#pragma unroll
    for (int i = 0; i < 4; ++i)
#pragma unroll
      for (int j = 0; j < 4; ++j) Ss[r4 + i][cg * 4 + j] = s_[i][j];
    __syncthreads();

    // row max (partial then combine)
    {
      int r = t >> 3, pp = t & 7;
      float pm = -3e38f;
#pragma unroll
      for (int k = 0; k < 16; ++k) pm = fmaxf(pm, Ss[r][pp * 16 + k]);
      red[r][pp] = pm;
    }
    __syncthreads();
    if (t < 32) {
      float tm = red[t][0];
#pragma unroll
      for (int j = 1; j < 8; ++j) tm = fmaxf(tm, red[t][j]);
      float om = Mrow[t];
      float nm = fmaxf(om, tm);
      Arow[t] = __expf(om - nm);
      Mrow[t] = nm;
    }
    __syncthreads();

    // P = exp(S - M) in-place, partial row sums
    {
      int r = t >> 3, pp = t & 7;
      float m = Mrow[r];
      float psum = 0.f;
#pragma unroll
      for (int k = 0; k < 16; ++k) {
        float pv = __expf(Ss[r][pp * 16 + k] - m);
        Ss[r][pp * 16 + k] = pv;
        psum += pv;
      }
      red[r][pp] = psum;
    }
    __syncthreads();
    if (t < 32) {
      float ts = 0.f;
#pragma unroll
      for (int j = 0; j < 8; ++j) ts += red[t][j];
      Lrow[t] = Lrow[t] * Arow[t] + ts;
    }

    // rescale y, then y += P @ g
    float al0 = Arow[r4 + 0], al1 = Arow[r4 + 1], al2 = Arow[r4 + 2], al3 = Arow[r4 + 3];
#pragma unroll
    for (int j = 0; j < 4; ++j) {
      yacc[0][j] *= al0; yacc[1][j] *= al1; yacc[2][j] *= al2; yacc[3][j] *= al3;
    }
    const float* gp = g_t + ((size_t)(b * Nn + m0)) * CIn + cg * 4;
#pragma unroll 2
    for (int mm = 0; mm < 128; ++mm) {
      float4 gv = *(const float4*)(gp + (size_t)mm * CIn);
      float p0 = Ss[r4 + 0][mm], p1 = Ss[r4 + 1][mm];
      float p2 = Ss[r4 + 2][mm], p3 = Ss[r4 + 3][mm];
      yacc[0][0] += p0 * gv.x; yacc[0][1] += p0 * gv.y; yacc[0][2] += p0 * gv.z; yacc[0][3] += p0 * gv.w;
      yacc[1][0] += p1 * gv.x; yacc[1][1] += p1 * gv.y; yacc[1][2] += p1 * gv.z; yacc[1][3] += p1 * gv.w;
      yacc[2][0] += p2 * gv.x; yacc[2][1] += p2 * gv.y; yacc[2][2] += p2 * gv.z; yacc[2][3] += p2 * gv.w;
      yacc[3][0] += p3 * gv.x; yacc[3][1] += p3 * gv.y; yacc[3][2] += p3 * gv.z; yacc[3][3] += p3 * gv.w;
    }
    __syncthreads();
  }

  // finalize: y[b][c][n] = yacc / L
#pragma unroll
  for (int i = 0; i < 4; ++i) {
    float linv = 1.f / Lrow[r4 + i];
#pragma unroll
    for (int j = 0; j < 4; ++j)
      y[((size_t)b * CIn + cg * 4 + j) * Nn + n0 + r4 + i] = yacc[i][j] * linv;
  }
}

// ---------------- final: out = GN2(wy)*0.1 + xs ----------------
__global__ __launch_bounds__(256) void k_final(
    const float* __restrict__ wy, const float* __restrict__ stats,
    const float* __restrict__ g2w, const float* __restrict__ g2b,
    const float* __restrict__ xs, float* __restrict__ out) {
  size_t i = ((size_t)blockIdx.x * 256 + threadIdx.x) * 4;
  int c = (int)((i >> 12) & 255);
  int bg = (int)(i >> 20) * Gn + (c >> 5);
  float mean = stats[bg * 2], rstd = stats[bg * 2 + 1];
  float sc = g2w[c] * rstd * 0.1f;
  float sb = (g2b[c] - mean * rstd * g2w[c]) * 0.1f;
  float4 v = *(const float4*)(wy + i);
  float4 xv = *(const float4*)(xs + i);
  v.x = v.x * sc + sb + xv.x;
  v.y = v.y * sc + sb + xv.y;
  v.z = v.z * sc + sb + xv.z;
  v.w = v.w * sc + sb + xv.w;
  *(float4*)(out + i) = v;
}

extern "C" void kernel_launch(void* const* d_in, const int* in_sizes, int n_in,
                              void* d_out, int out_size, void* d_ws, size_t ws_size,
                              hipStream_t stream) {
  (void)in_sizes; (void)n_in; (void)out_size; (void)ws_size;
  const float* x   = (const float*)d_in[0];
  const float* sw  = (const float*)d_in[1];
  const float* sb  = (const float*)d_in[2];
  const float* g1w = (const float*)d_in[3];
  const float* g1b = (const float*)d_in[4];
  const float* gw  = (const float*)d_in[5];
  const float* gb  = (const float*)d_in[6];
  const float* thw = (const float*)d_in[7];
  const float* thb = (const float*)d_in[8];
  const float* phw = (const float*)d_in[9];
  const float* phb = (const float*)d_in[10];
  const float* ww  = (const float*)d_in[11];
  const float* wb  = (const float*)d_in[12];
  const float* g2w = (const float*)d_in[13];
  const float* g2b = (const float*)d_in[14];
  float* out = (float*)d_out;
  float* ws = (float*)d_ws;

  float* xs_raw  = ws;                  // 4,194,304 f (aliased as wy later)
  float* xs      = ws + 4194304;        // 4,194,304 f
  float* theta_t = ws + 8388608;        // 2,097,152 f  [B][N][CI]
  float* g_t     = ws + 10485760;       // 2,097,152 f  [B][N][CI]
  float* phi_    = ws + 12582912;       // 2,097,152 f  [B][CI][N]
  float* y_      = ws + 14680064;       // 2,097,152 f  [B][CI][N]
  float* part    = ws + 16777216;       // 1024 f
  float* st1     = ws + 16778240;       // 64 f
  float* st2     = ws + 16778304;       // 64 f
  float* wy      = xs_raw;              // reuse (xs_raw dead after gn1 apply)

  k_conv3x3<<<dim3(4, 64, 4), 256, 0, stream>>>(x, sw, sb, xs_raw);
  k_gn_part<<<dim3(16, 8, 4), 256, 0, stream>>>(xs_raw, part);
  k_gn_final<<<1, 64, 0, stream>>>(part, st1);
  k_gn1_apply<<<4096, 256, 0, stream>>>(xs_raw, st1, g1w, g1b, xs);
  k_proj<<<dim3(64, 3, 4), 256, 0, stream>>>(xs, thw, thb, gw, gb, phw, phb,
                                             theta_t, g_t, phi_);
  k_attn<<<dim3(128, 4), 256, 0, stream>>>(theta_t, phi_, g_t, y_);
  k_wconv<<<dim3(64, 2, 4), 256, 0, stream>>>(y_, ww, wb, wy);
  k_gn_part<<<dim3(16, 8, 4), 256, 0, stream>>>(wy, part);
  k_gn_final<<<1, 64, 0, stream>>>(part, st2);
  k_final<<<4096, 256, 0, stream>>>(wy, st2, g2w, g2b, xs, out);
}

// Round 3
// 805.472 us; speedup vs baseline: 2.2833x; 2.2833x over previous
//
#include <hip/hip_runtime.h>
#include <math.h>

#define Bn 4
#define Cn 256
#define CIn 128
#define Hn 64
#define Wn 64
#define Nn 4096
#define Gn 8
#define CPGn 32
#define EPSc 1e-5f

typedef unsigned short ushort_t;
typedef short bfrag __attribute__((ext_vector_type(8)));       // 8 bf16 (4 VGPRs)
typedef float f32x4 __attribute__((ext_vector_type(4)));
typedef ushort_t u16x4 __attribute__((ext_vector_type(4)));
typedef ushort_t u16x8 __attribute__((ext_vector_type(8)));

static __device__ __forceinline__ ushort_t f2bf(float f) {
  unsigned u = __float_as_uint(f);
  return (ushort_t)((u + 0x7FFFu + ((u >> 16) & 1u)) >> 16);   // RNE
}

// ---------------- conv3x3 + bias ----------------
__global__ __launch_bounds__(256) void k_conv3x3(
    const float* __restrict__ x, const float* __restrict__ w3,
    const float* __restrict__ b3, float* __restrict__ out) {
  __shared__ float lx[32][3][68];
  const int t = threadIdx.x;
  const int cb = blockIdx.x, h = blockIdx.y, b = blockIdx.z;
  const int co = cb * 64 + (t >> 2);
  const int w4 = (t & 3) * 16;
  float acc[16];
#pragma unroll
  for (int k = 0; k < 16; ++k) acc[k] = 0.f;

  for (int cc = 0; cc < 8; ++cc) {
    for (int i = t; i < 32 * 3 * 68; i += 256) {
      int ci = i / 204, rem = i % 204, dh = rem / 68, j = rem % 68;
      int hh = h + dh - 1, ww = j - 1;
      float v = 0.f;
      if (j < 66 && hh >= 0 && hh < Hn && ww >= 0 && ww < Wn)
        v = x[(((size_t)b * Cn + cc * 32 + ci) * Hn + hh) * Wn + ww];
      lx[ci][dh][j] = v;
    }
    __syncthreads();
    for (int ci = 0; ci < 32; ++ci) {
      const float* wp = w3 + ((size_t)co * Cn + cc * 32 + ci) * 9;
#pragma unroll
      for (int dh = 0; dh < 3; ++dh) {
        float rr[18];
#pragma unroll
        for (int j = 0; j < 18; ++j) rr[j] = lx[ci][dh][w4 + j];
        float w0 = wp[dh * 3 + 0], w1 = wp[dh * 3 + 1], w2 = wp[dh * 3 + 2];
#pragma unroll
        for (int k = 0; k < 16; ++k)
          acc[k] += w0 * rr[k] + w1 * rr[k + 1] + w2 * rr[k + 2];
      }
    }
    __syncthreads();
  }
  const float bias = b3[co];
  float* op = out + ((size_t)b * Cn + co) * Nn + h * Wn + w4;
#pragma unroll
  for (int k = 0; k < 16; ++k) op[k] = acc[k] + bias;
}

// ---------------- GroupNorm stats ----------------
__global__ __launch_bounds__(256) void k_gn_part(
    const float* __restrict__ xin, float* __restrict__ part) {
  const int s = blockIdx.x, g = blockIdx.y, b = blockIdx.z;
  const int t = threadIdx.x;
  const float* p = xin + ((size_t)b * Cn + g * CPGn) * Nn + s * 8192;
  float sum = 0.f, ssq = 0.f;
  for (int i = t * 4; i < 8192; i += 1024) {
    float4 v = *(const float4*)(p + i);
    sum += v.x + v.y + v.z + v.w;
    ssq += v.x * v.x + v.y * v.y + v.z * v.z + v.w * v.w;
  }
  __shared__ float r1[256], r2[256];
  r1[t] = sum; r2[t] = ssq;
  __syncthreads();
  for (int st = 128; st > 0; st >>= 1) {
    if (t < st) { r1[t] += r1[t + st]; r2[t] += r2[t + st]; }
    __syncthreads();
  }
  if (t == 0) {
    size_t idx = ((size_t)(b * Gn + g) * 16 + s) * 2;
    part[idx] = r1[0];
    part[idx + 1] = r2[0];
  }
}

__global__ void k_gn_final(const float* __restrict__ part, float* __restrict__ stats) {
  const int t = threadIdx.x;
  if (t < Bn * Gn) {
    float s = 0.f, ss = 0.f;
    for (int j = 0; j < 16; ++j) {
      s += part[(t * 16 + j) * 2];
      ss += part[(t * 16 + j) * 2 + 1];
    }
    const float inv = 1.f / (float)(CPGn * Nn);
    float mean = s * inv;
    float var = ss * inv - mean * mean;
    stats[t * 2] = mean;
    stats[t * 2 + 1] = rsqrtf(var + EPSc);
  }
}

// ---------------- GN1 apply + ReLU ----------------
__global__ __launch_bounds__(256) void k_gn1_apply(
    const float* __restrict__ xr, const float* __restrict__ stats,
    const float* __restrict__ gw, const float* __restrict__ gb,
    float* __restrict__ xs) {
  size_t i = ((size_t)blockIdx.x * 256 + threadIdx.x) * 4;
  int c = (int)((i >> 12) & 255);
  int bg = (int)(i >> 20) * Gn + (c >> 5);
  float mean = stats[bg * 2], rstd = stats[bg * 2 + 1];
  float sc = gw[c] * rstd;
  float sb = gb[c] - mean * sc;
  float4 v = *(const float4*)(xr + i);
  v.x = fmaxf(v.x * sc + sb, 0.f);
  v.y = fmaxf(v.y * sc + sb, 0.f);
  v.z = fmaxf(v.z * sc + sb, 0.f);
  v.w = fmaxf(v.w * sc + sb, 0.f);
  *(float4*)(xs + i) = v;
}

// ---------------- fp32 GEMM tile (used by k_wconv) ----------------
__device__ __forceinline__ void gemm_tile(
    const float* __restrict__ Wm, const float* __restrict__ bias,
    const float* __restrict__ Xb, float* __restrict__ outb,
    const int K, const int mb, const int nb) {
  __shared__ float Xs[32][64];
  __shared__ float Ws[128][33];
  const int t = threadIdx.x;
  const int m0 = (t >> 4) * 8, n0 = (t & 15) * 4;
  float acc[8][4];
#pragma unroll
  for (int i = 0; i < 8; ++i)
#pragma unroll
    for (int j = 0; j < 4; ++j) acc[i][j] = 0.f;

  for (int k0 = 0; k0 < K; k0 += 32) {
    for (int i = t; i < 2048; i += 256)
      Xs[i >> 6][i & 63] = Xb[(size_t)(k0 + (i >> 6)) * Nn + nb * 64 + (i & 63)];
    for (int i = t; i < 4096; i += 256)
      Ws[i >> 5][i & 31] = Wm[(size_t)(mb * 128 + (i >> 5)) * K + k0 + (i & 31)];
    __syncthreads();
#pragma unroll 4
    for (int kk = 0; kk < 32; ++kk) {
      float4 xv = *(const float4*)&Xs[kk][n0];
#pragma unroll
      for (int i = 0; i < 8; ++i) {
        float wv = Ws[m0 + i][kk];
        acc[i][0] += wv * xv.x; acc[i][1] += wv * xv.y;
        acc[i][2] += wv * xv.z; acc[i][3] += wv * xv.w;
      }
    }
    __syncthreads();
  }
#pragma unroll
  for (int i = 0; i < 8; ++i) {
    float bv = bias[mb * 128 + m0 + i];
#pragma unroll
    for (int j = 0; j < 4; ++j)
      outb[(size_t)(mb * 128 + m0 + i) * Nn + nb * 64 + n0 + j] = acc[i][j] + bv;
  }
}

// ---------------- projections -> bf16 (theta/phi [N][Ci], g [Ci][N]) ----------------
__global__ __launch_bounds__(256) void k_proj_bf16(
    const float* __restrict__ xs,
    const float* __restrict__ thw, const float* __restrict__ thb,
    const float* __restrict__ phw, const float* __restrict__ phb,
    const float* __restrict__ gww, const float* __restrict__ gbb,
    ushort_t* __restrict__ theta_b, ushort_t* __restrict__ phi_b,
    ushort_t* __restrict__ g_b) {
  const int nb = blockIdx.x, which = blockIdx.y, b = blockIdx.z;
  const float* Xb = xs + (size_t)b * Cn * Nn;
  const float* Wm = (which == 0) ? thw : (which == 1) ? phw : gww;
  const float* bs = (which == 0) ? thb : (which == 1) ? phb : gbb;

  __shared__ float Xs[32][64];
  __shared__ float Ws[128][33];
  const int t = threadIdx.x;
  const int m0 = (t >> 4) * 8, n0 = (t & 15) * 4;
  float acc[8][4];
#pragma unroll
  for (int i = 0; i < 8; ++i)
#pragma unroll
    for (int j = 0; j < 4; ++j) acc[i][j] = 0.f;

  for (int k0 = 0; k0 < Cn; k0 += 32) {
    for (int i = t; i < 2048; i += 256)
      Xs[i >> 6][i & 63] = Xb[(size_t)(k0 + (i >> 6)) * Nn + nb * 64 + (i & 63)];
    for (int i = t; i < 4096; i += 256)
      Ws[i >> 5][i & 31] = Wm[(size_t)(i >> 5) * Cn + k0 + (i & 31)];
    __syncthreads();
#pragma unroll 4
    for (int kk = 0; kk < 32; ++kk) {
      float4 xv = *(const float4*)&Xs[kk][n0];
#pragma unroll
      for (int i = 0; i < 8; ++i) {
        float wv = Ws[m0 + i][kk];
        acc[i][0] += wv * xv.x; acc[i][1] += wv * xv.y;
        acc[i][2] += wv * xv.z; acc[i][3] += wv * xv.w;
      }
    }
    __syncthreads();
  }

  if (which < 2) {
    ushort_t* ob = ((which == 0) ? theta_b : phi_b) + (size_t)b * Nn * CIn;
#pragma unroll
    for (int j = 0; j < 4; ++j) {
      u16x8 pk;
#pragma unroll
      for (int i = 0; i < 8; ++i) pk[i] = f2bf(acc[i][j] + bs[m0 + i]);
      *(u16x8*)(ob + (size_t)(nb * 64 + n0 + j) * CIn + m0) = pk;
    }
  } else {
    ushort_t* ob = g_b + (size_t)b * CIn * Nn;
#pragma unroll
    for (int i = 0; i < 8; ++i) {
      float bv = bs[m0 + i];
      u16x4 pk;
#pragma unroll
      for (int j = 0; j < 4; ++j) pk[j] = f2bf(acc[i][j] + bv);
      *(u16x4*)(ob + (size_t)(m0 + i) * Nn + nb * 64 + n0) = pk;
    }
  }
}

// ---------------- MFMA flash attention (bf16) ----------------
// grid (64, 4): 256 blocks, 4 waves, QBLK=64 (16 q-rows/wave), KVBLK=64.
__global__ __launch_bounds__(256) void k_attn_mfma(
    const ushort_t* __restrict__ theta_b, const ushort_t* __restrict__ phi_b,
    const ushort_t* __restrict__ g_b, float* __restrict__ y) {
  __shared__ __align__(16) ushort_t lphi[64 * 128];   // [m][d], swz ^((m&7)<<4)
  __shared__ __align__(16) ushort_t lg[128 * 64];     // [d][m], swz ^((d&7)<<4)
  __shared__ __align__(16) ushort_t lP[4][16 * 64];   // per-wave [q][m], swz ^((q&7)<<4)

  const int tid = threadIdx.x;
  const int lane = tid & 63, w = tid >> 6;
  const int ln = lane & 15, lhi = lane >> 4;

  // bijective XCD remap: each XCD's L2 serves one batch (phi+g = 2 MB)
  const int lid = blockIdx.x + 64 * blockIdx.y;
  const int xcd = lid & 7, slot = lid >> 3;
  const int b = xcd >> 1;
  const int n0 = ((xcd & 1) * 32 + slot) * 64;

  // Q fragments in registers
  bfrag qf[4];
  {
    const ushort_t* thp =
        theta_b + ((size_t)(b * Nn + n0 + w * 16 + ln)) * CIn + 8 * lhi;
#pragma unroll
    for (int kb = 0; kb < 4; ++kb) qf[kb] = *(const bfrag*)(thp + kb * 32);
  }

  f32x4 yacc[8];
#pragma unroll
  for (int df = 0; df < 8; ++df) yacc[df] = (f32x4){0.f, 0.f, 0.f, 0.f};
  float mrow[4] = {-3e38f, -3e38f, -3e38f, -3e38f};
  float lrow[4] = {0.f, 0.f, 0.f, 0.f};

  // staging: phi 64 rows x 16 chunks, g 128 rows x 8 chunks (16B each)
  const int pm_ = tid >> 4, pch = tid & 15;
  const int gd_ = tid >> 3, gch = tid & 7;
  const ushort_t* phiBase = phi_b + (size_t)b * Nn * CIn + (size_t)pm_ * CIn + pch * 8;
  const ushort_t* gBase   = g_b   + (size_t)b * CIn * Nn + (size_t)gd_ * Nn + gch * 8;
  uint4 rp[4], rg[4];
  int offp[4], offg[4];
#pragma unroll
  for (int it = 0; it < 4; ++it) {
    offp[it] = (((pm_ + it * 16) * 128 + pch * 8) * 2) ^ ((pm_ & 7) << 4);
    offg[it] = (((gd_ + it * 32) * 64 + gch * 8) * 2) ^ ((gd_ & 7) << 4);
  }
#pragma unroll
  for (int it = 0; it < 4; ++it) {
    rp[it] = *(const uint4*)(phiBase + (size_t)it * 16 * CIn);
    rg[it] = *(const uint4*)(gBase + (size_t)it * 32 * Nn);
  }

  ushort_t* lPw = lP[w];

  for (int t = 0; t < 64; ++t) {
    __syncthreads();                       // prior tile's LDS reads done
#pragma unroll
    for (int it = 0; it < 4; ++it) {
      *(uint4*)((char*)lphi + offp[it]) = rp[it];
      *(uint4*)((char*)lg + offg[it]) = rg[it];
    }
    if (t < 63) {                          // T14: issue next-tile loads early
      const int m1 = (t + 1) * 64;
#pragma unroll
      for (int it = 0; it < 4; ++it) {
        rp[it] = *(const uint4*)(phiBase + (size_t)(m1 + it * 16) * CIn);
        rg[it] = *(const uint4*)(gBase + m1 + (size_t)it * 32 * Nn);
      }
    }
    __syncthreads();                       // tile ready

    // ---- S = theta · phi^T : 16x64 per wave ----
    f32x4 sacc[4];
#pragma unroll
    for (int nf = 0; nf < 4; ++nf) sacc[nf] = (f32x4){0.f, 0.f, 0.f, 0.f};
    __builtin_amdgcn_s_setprio(1);
#pragma unroll
    for (int kb = 0; kb < 4; ++kb) {
#pragma unroll
      for (int nf = 0; nf < 4; ++nf) {
        int row = nf * 16 + ln;
        int off = ((row * 128 + kb * 32 + 8 * lhi) * 2) ^ ((ln & 7) << 4);
        bfrag pf = *(const bfrag*)((const char*)lphi + off);
        sacc[nf] = __builtin_amdgcn_mfma_f32_16x16x32_bf16(qf[kb], pf, sacc[nf], 0, 0, 0);
      }
    }
    __builtin_amdgcn_s_setprio(0);

    // ---- online softmax (rows spread over regs; reduce across 16 lanes) ----
    float aa[4], ps[4];
#pragma unroll
    for (int r = 0; r < 4; ++r) {
      float v = fmaxf(fmaxf(sacc[0][r], sacc[1][r]), fmaxf(sacc[2][r], sacc[3][r]));
      v = fmaxf(v, __shfl_xor(v, 1));
      v = fmaxf(v, __shfl_xor(v, 2));
      v = fmaxf(v, __shfl_xor(v, 4));
      v = fmaxf(v, __shfl_xor(v, 8));
      float nm = fmaxf(mrow[r], v);
      aa[r] = __expf(mrow[r] - nm);
      mrow[r] = nm;
      ps[r] = 0.f;
    }
#pragma unroll
    for (int nf = 0; nf < 4; ++nf) {
#pragma unroll
      for (int r = 0; r < 4; ++r) {
        float p = __expf(sacc[nf][r] - mrow[r]);
        ps[r] += p;
        int q = lhi * 4 + r;
        int off = ((q * 64 + nf * 16 + ln) * 2) ^ ((q & 7) << 4);
        *(ushort_t*)((char*)lPw + off) = f2bf(p);
      }
    }
#pragma unroll
    for (int r = 0; r < 4; ++r) {
      float v = ps[r];
      v += __shfl_xor(v, 1);
      v += __shfl_xor(v, 2);
      v += __shfl_xor(v, 4);
      v += __shfl_xor(v, 8);
      lrow[r] = lrow[r] * aa[r] + v;
    }
#pragma unroll
    for (int df = 0; df < 8; ++df)
#pragma unroll
      for (int r = 0; r < 4; ++r) yacc[df][r] *= aa[r];

    // ---- y += P · g^T(rows=d) ----
    __builtin_amdgcn_s_setprio(1);
#pragma unroll
    for (int kb2 = 0; kb2 < 2; ++kb2) {
      int offa = ((ln * 64 + kb2 * 32 + 8 * lhi) * 2) ^ ((ln & 7) << 4);
      bfrag pa = *(const bfrag*)((const char*)lPw + offa);
#pragma unroll
      for (int df = 0; df < 8; ++df) {
        int d = df * 16 + ln;
        int offb = ((d * 64 + kb2 * 32 + 8 * lhi) * 2) ^ ((ln & 7) << 4);
        bfrag gbf = *(const bfrag*)((const char*)lg + offb);
        yacc[df] = __builtin_amdgcn_mfma_f32_16x16x32_bf16(pa, gbf, yacc[df], 0, 0, 0);
      }
    }
    __builtin_amdgcn_s_setprio(0);
  }

  // ---- epilogue: y[b][d][n] = yacc / l ----
#pragma unroll
  for (int r = 0; r < 4; ++r) lrow[r] = 1.f / lrow[r];
  float* yp = y + (size_t)b * CIn * Nn + n0 + w * 16 + lhi * 4;
#pragma unroll
  for (int df = 0; df < 8; ++df)
#pragma unroll
    for (int r = 0; r < 4; ++r)
      yp[(size_t)(df * 16 + ln) * Nn + r] = yacc[df][r] * lrow[r];
}

// ---------------- final 1x1: wy = w_w @ y + w_b ----------------
__global__ __launch_bounds__(256) void k_wconv(
    const float* __restrict__ y, const float* __restrict__ ww,
    const float* __restrict__ wb, float* __restrict__ wy) {
  const int nb = blockIdx.x, mb = blockIdx.y, b = blockIdx.z;
  gemm_tile(ww, wb, y + (size_t)b * CIn * Nn, wy + (size_t)b * Cn * Nn, CIn, mb, nb);
}

// ---------------- final: out = GN2(wy)*0.1 + xs ----------------
__global__ __launch_bounds__(256) void k_final(
    const float* __restrict__ wy, const float* __restrict__ stats,
    const float* __restrict__ g2w, const float* __restrict__ g2b,
    const float* __restrict__ xs, float* __restrict__ out) {
  size_t i = ((size_t)blockIdx.x * 256 + threadIdx.x) * 4;
  int c = (int)((i >> 12) & 255);
  int bg = (int)(i >> 20) * Gn + (c >> 5);
  float mean = stats[bg * 2], rstd = stats[bg * 2 + 1];
  float sc = g2w[c] * rstd * 0.1f;
  float sb = (g2b[c] - mean * rstd * g2w[c]) * 0.1f;
  float4 v = *(const float4*)(wy + i);
  float4 xv = *(const float4*)(xs + i);
  v.x = v.x * sc + sb + xv.x;
  v.y = v.y * sc + sb + xv.y;
  v.z = v.z * sc + sb + xv.z;
  v.w = v.w * sc + sb + xv.w;
  *(float4*)(out + i) = v;
}

extern "C" void kernel_launch(void* const* d_in, const int* in_sizes, int n_in,
                              void* d_out, int out_size, void* d_ws, size_t ws_size,
                              hipStream_t stream) {
  (void)in_sizes; (void)n_in; (void)out_size; (void)ws_size;
  const float* x   = (const float*)d_in[0];
  const float* sw  = (const float*)d_in[1];
  const float* sb  = (const float*)d_in[2];
  const float* g1w = (const float*)d_in[3];
  const float* g1b = (const float*)d_in[4];
  const float* gw  = (const float*)d_in[5];
  const float* gb  = (const float*)d_in[6];
  const float* thw = (const float*)d_in[7];
  const float* thb = (const float*)d_in[8];
  const float* phw = (const float*)d_in[9];
  const float* phb = (const float*)d_in[10];
  const float* ww  = (const float*)d_in[11];
  const float* wb  = (const float*)d_in[12];
  const float* g2w = (const float*)d_in[13];
  const float* g2b = (const float*)d_in[14];
  float* out = (float*)d_out;
  float* ws = (float*)d_ws;

  float*    xs_raw  = ws;                              // 4,194,304 f (reused as wy)
  float*    xs      = ws + 4194304;                    // 4,194,304 f
  float*    y_      = ws + 8388608;                    // 2,097,152 f  [B][Ci][N]
  float*    part    = ws + 10485760;                   // 1024 f
  float*    st1     = ws + 10486784;                   // 64 f
  float*    st2     = ws + 10486848;                   // 64 f
  ushort_t* theta_b = (ushort_t*)(ws + 10486912);      // 2,097,152 u16 [B][N][Ci]
  ushort_t* phi_b   = (ushort_t*)(ws + 11535488);      // 2,097,152 u16 [B][N][Ci]
  ushort_t* g_b     = (ushort_t*)(ws + 12584064);      // 2,097,152 u16 [B][Ci][N]
  float*    wy      = xs_raw;

  k_conv3x3<<<dim3(4, 64, 4), 256, 0, stream>>>(x, sw, sb, xs_raw);
  k_gn_part<<<dim3(16, 8, 4), 256, 0, stream>>>(xs_raw, part);
  k_gn_final<<<1, 64, 0, stream>>>(part, st1);
  k_gn1_apply<<<4096, 256, 0, stream>>>(xs_raw, st1, g1w, g1b, xs);
  k_proj_bf16<<<dim3(64, 3, 4), 256, 0, stream>>>(xs, thw, thb, phw, phb, gw, gb,
                                                  theta_b, phi_b, g_b);
  k_attn_mfma<<<dim3(64, 4), 256, 0, stream>>>(theta_b, phi_b, g_b, y_);
  k_wconv<<<dim3(64, 2, 4), 256, 0, stream>>>(y_, ww, wb, wy);
  k_gn_part<<<dim3(16, 8, 4), 256, 0, stream>>>(wy, part);
  k_gn_final<<<1, 64, 0, stream>>>(part, st2);
  k_final<<<4096, 256, 0, stream>>>(wy, st2, g2w, g2b, xs, out);
}

// Round 4
// 331.541 us; speedup vs baseline: 5.5472x; 2.4295x over previous
//
#include <hip/hip_runtime.h>
#include <math.h>

#define Bn 4
#define Cn 256
#define CIn 128
#define Hn 64
#define Wn 64
#define Nn 4096
#define Gn 8
#define CPGn 32
#define EPSc 1e-5f

typedef unsigned short ushort_t;
typedef short bfrag __attribute__((ext_vector_type(8)));       // 8 bf16 (4 VGPRs)
typedef float f32x4 __attribute__((ext_vector_type(4)));
typedef ushort_t u16x8 __attribute__((ext_vector_type(8)));

static __device__ __forceinline__ ushort_t f2bf(float f) {
  unsigned u = __float_as_uint(f);
  return (ushort_t)((u + 0x7FFFu + ((u >> 16) & 1u)) >> 16);   // RNE
}

// ---------------- weight prepack (fp32 -> bf16, rearranged) ----------------
// w3[co][ci][3][3] -> w9[tap][co][ci]; proj W[128][256]x3 -> wp9; ww[256][128] -> wwb
__global__ __launch_bounds__(256) void k_prepack(
    const float* __restrict__ w3, const float* __restrict__ thw,
    const float* __restrict__ phw, const float* __restrict__ gww,
    const float* __restrict__ ww,
    ushort_t* __restrict__ w9, ushort_t* __restrict__ wp9,
    ushort_t* __restrict__ wwb) {
  int i = blockIdx.x * 256 + threadIdx.x;
  if (i < 589824) {
    float v = w3[i];
    int co = i / 2304, r = i % 2304, ci = r / 9, tap = r % 9;
    w9[tap * 65536 + co * 256 + ci] = f2bf(v);
  } else if (i < 688128) {
    int j = i - 589824;
    int which = j >> 15, r = j & 32767;
    const float* src = (which == 0) ? thw : (which == 1) ? phw : gww;
    wp9[j] = f2bf(src[r]);
  } else if (i < 720896) {
    int j = i - 688128;
    wwb[j] = f2bf(ww[j]);
  }
}

// ---------------- conv3x3 via implicit-GEMM MFMA ----------------
// grid (Hn, Bn), 512 thr / 8 waves; wave w -> co [w*32, w*32+32), all 64 w-positions.
__global__ __launch_bounds__(512) void k_conv_mfma(
    const float* __restrict__ x, const ushort_t* __restrict__ w9,
    const float* __restrict__ b3, float* __restrict__ out) {
  __shared__ __align__(16) ushort_t lx[3 * 66 * 128];   // [dh][wp][ci], byte swz ^((wp&7)<<4)
  const int tid = threadIdx.x;
  const int lane = tid & 63, w = tid >> 6;
  const int ln = lane & 15, lhi = lane >> 4;
  const int h = blockIdx.x, b = blockIdx.y;
  const int wco = w * 32;

  f32x4 acc[2][4];
#pragma unroll
  for (int mf = 0; mf < 2; ++mf)
#pragma unroll
    for (int nf = 0; nf < 4; ++nf) acc[mf][nf] = (f32x4){0.f, 0.f, 0.f, 0.f};

  for (int cc = 0; cc < 2; ++cc) {
    __syncthreads();                     // previous chunk's reads done
    // zero left/right pad columns (wp = 0, 65)
    for (int i = tid; i < 768; i += 512) {
      int dh = i / 256, r = i % 256, wpz = (r >> 7) ? 65 : 0, ci = r & 127;
      int off = (((dh * 66 + wpz) * 128 + ci) * 2) ^ ((wpz & 7) << 4);
      *(ushort_t*)((char*)lx + off) = 0;
    }
    // stage 3 rows x 64 w x 128 ci (fp32 -> bf16)
    for (int i = tid; i < 6144; i += 512) {
      int dh = i >> 11, r = i & 2047, ci = r >> 4, w4 = (r & 15) * 4;
      int hh = h + dh - 1;
      float4 v = {0.f, 0.f, 0.f, 0.f};
      if (hh >= 0 && hh < Hn)
        v = *(const float4*)(x + (((size_t)(b * Cn + cc * 128 + ci)) * Hn + hh) * Wn + w4);
      float vv[4] = {v.x, v.y, v.z, v.w};
#pragma unroll
      for (int j = 0; j < 4; ++j) {
        int wp = 1 + w4 + j;
        int off = (((dh * 66 + wp) * 128 + ci) * 2) ^ ((wp & 7) << 4);
        *(ushort_t*)((char*)lx + off) = f2bf(vv[j]);
      }
    }
    __syncthreads();

#pragma unroll
    for (int tap = 0; tap < 9; ++tap) {
      const int dh = tap / 3, dw = tap % 3;
#pragma unroll
      for (int kb = 0; kb < 4; ++kb) {
        const ushort_t* ap = w9 + tap * 65536 + (size_t)(wco + ln) * 256 +
                             cc * 128 + kb * 32 + lhi * 8;
        bfrag af0 = *(const bfrag*)ap;
        bfrag af1 = *(const bfrag*)(ap + 16 * 256);
        __builtin_amdgcn_s_setprio(1);
#pragma unroll
        for (int nf = 0; nf < 4; ++nf) {
          int wp = nf * 16 + ln + dw;
          int off = (((dh * 66 + wp) * 128 + kb * 32 + lhi * 8) * 2) ^ ((wp & 7) << 4);
          bfrag bf = *(const bfrag*)((const char*)lx + off);
          acc[0][nf] = __builtin_amdgcn_mfma_f32_16x16x32_bf16(af0, bf, acc[0][nf], 0, 0, 0);
          acc[1][nf] = __builtin_amdgcn_mfma_f32_16x16x32_bf16(af1, bf, acc[1][nf], 0, 0, 0);
        }
        __builtin_amdgcn_s_setprio(0);
      }
    }
  }

  // epilogue: co = wco + mf*16 + lhi*4 + r; hw = nf*16 + ln
#pragma unroll
  for (int mf = 0; mf < 2; ++mf) {
    float4 bv = *(const float4*)(b3 + wco + mf * 16 + lhi * 4);
    float bb[4] = {bv.x, bv.y, bv.z, bv.w};
#pragma unroll
    for (int nf = 0; nf < 4; ++nf) {
#pragma unroll
      for (int r = 0; r < 4; ++r) {
        int co = wco + mf * 16 + lhi * 4 + r;
        out[((size_t)(b * Cn + co)) * Nn + h * Wn + nf * 16 + ln] = acc[mf][nf][r] + bb[r];
      }
    }
  }
}

// ---------------- GroupNorm stats ----------------
__global__ __launch_bounds__(256) void k_gn_part(
    const float* __restrict__ xin, float* __restrict__ part) {
  const int s = blockIdx.x, g = blockIdx.y, b = blockIdx.z;
  const int t = threadIdx.x;
  const float* p = xin + ((size_t)b * Cn + g * CPGn) * Nn + s * 8192;
  float sum = 0.f, ssq = 0.f;
  for (int i = t * 4; i < 8192; i += 1024) {
    float4 v = *(const float4*)(p + i);
    sum += v.x + v.y + v.z + v.w;
    ssq += v.x * v.x + v.y * v.y + v.z * v.z + v.w * v.w;
  }
  __shared__ float r1[256], r2[256];
  r1[t] = sum; r2[t] = ssq;
  __syncthreads();
  for (int st = 128; st > 0; st >>= 1) {
    if (t < st) { r1[t] += r1[t + st]; r2[t] += r2[t + st]; }
    __syncthreads();
  }
  if (t == 0) {
    size_t idx = ((size_t)(b * Gn + g) * 16 + s) * 2;
    part[idx] = r1[0];
    part[idx + 1] = r2[0];
  }
}

__global__ void k_gn_final(const float* __restrict__ part, float* __restrict__ stats) {
  const int t = threadIdx.x;
  if (t < Bn * Gn) {
    float s = 0.f, ss = 0.f;
    for (int j = 0; j < 16; ++j) {
      s += part[(t * 16 + j) * 2];
      ss += part[(t * 16 + j) * 2 + 1];
    }
    const float inv = 1.f / (float)(CPGn * Nn);
    float mean = s * inv;
    float var = ss * inv - mean * mean;
    stats[t * 2] = mean;
    stats[t * 2 + 1] = rsqrtf(var + EPSc);
  }
}

// ---------------- GN1 apply + ReLU -> xs (fp32) and xsT (bf16 [B][N][C]) ----------------
// grid (64 ntiles, 8 ctiles, 4 b), 256 thr.
__global__ __launch_bounds__(256) void k_gn1_apply_t(
    const float* __restrict__ xr, const float* __restrict__ stats,
    const float* __restrict__ gw, const float* __restrict__ gb,
    float* __restrict__ xs, ushort_t* __restrict__ xsT) {
  __shared__ ushort_t lt[32 * 64];
  const int t = threadIdx.x;
  const int n0 = blockIdx.x * 64, c0 = blockIdx.y * 32, b = blockIdx.z;
#pragma unroll
  for (int p = 0; p < 8; ++p) {
    int c = c0 + p * 4 + (t >> 6);
    int n = n0 + (t & 63);
    int bg = b * Gn + (c >> 5);
    float mean = stats[bg * 2], rstd = stats[bg * 2 + 1];
    float sc = gw[c] * rstd;
    float sb = gb[c] - mean * sc;
    size_t idx = ((size_t)(b * Cn + c)) * Nn + n;
    float val = fmaxf(xr[idx] * sc + sb, 0.f);
    xs[idx] = val;
    lt[(c - c0) * 64 + (t & 63)] = f2bf(val);
  }
  __syncthreads();
  {
    int n = t >> 2, cg = t & 3;
    u16x8 pk;
#pragma unroll
    for (int j = 0; j < 8; ++j) pk[j] = lt[(cg * 8 + j) * 64 + n];
    *(u16x8*)(xsT + ((size_t)(b * Nn + n0 + n)) * Cn + c0 + cg * 8) = pk;
  }
}

// ---------------- projections via MFMA: theta/phi [N][Ci] bf16, g [Ci][N] bf16 ----------------
// grid (64 ntiles, 3 which, 4 b), 256 thr / 4 waves; wave -> ci rows w*32.
__global__ __launch_bounds__(256) void k_proj_mfma(
    const ushort_t* __restrict__ xsT, const ushort_t* __restrict__ wp9,
    const float* __restrict__ thb, const float* __restrict__ phb,
    const float* __restrict__ gbb,
    ushort_t* __restrict__ theta_b, ushort_t* __restrict__ phi_b,
    ushort_t* __restrict__ g_b) {
  __shared__ __align__(16) ushort_t lxs[64 * 256];   // [n][c], swz ^((n&7)<<4)
  const int tid = threadIdx.x;
  const int lane = tid & 63, w = tid >> 6;
  const int ln = lane & 15, lhi = lane >> 4;
  const int n0 = blockIdx.x * 64, which = blockIdx.y, b = blockIdx.z;
  const int wci = w * 32;

  for (int i = tid; i < 2048; i += 256) {
    int n = i >> 5, cchunk = (i & 31) * 8;
    uint4 v = *(const uint4*)(xsT + ((size_t)(b * Nn + n0 + n)) * Cn + cchunk);
    int off = ((n * 256 + cchunk) * 2) ^ ((n & 7) << 4);
    *(uint4*)((char*)lxs + off) = v;
  }
  __syncthreads();

  f32x4 acc[2][4];
#pragma unroll
  for (int mf = 0; mf < 2; ++mf)
#pragma unroll
    for (int nf = 0; nf < 4; ++nf) acc[mf][nf] = (f32x4){0.f, 0.f, 0.f, 0.f};

#pragma unroll
  for (int kb = 0; kb < 8; ++kb) {
    const ushort_t* ap = wp9 + which * 32768 + (size_t)(wci + ln) * 256 + kb * 32 + lhi * 8;
    bfrag af0 = *(const bfrag*)ap;
    bfrag af1 = *(const bfrag*)(ap + 16 * 256);
    __builtin_amdgcn_s_setprio(1);
#pragma unroll
    for (int nf = 0; nf < 4; ++nf) {
      int n = nf * 16 + ln;
      int off = ((n * 256 + kb * 32 + lhi * 8) * 2) ^ ((n & 7) << 4);
      bfrag bf = *(const bfrag*)((const char*)lxs + off);
      acc[0][nf] = __builtin_amdgcn_mfma_f32_16x16x32_bf16(af0, bf, acc[0][nf], 0, 0, 0);
      acc[1][nf] = __builtin_amdgcn_mfma_f32_16x16x32_bf16(af1, bf, acc[1][nf], 0, 0, 0);
    }
    __builtin_amdgcn_s_setprio(0);
  }

  const float* bs = (which == 0) ? thb : (which == 1) ? phb : gbb;
#pragma unroll
  for (int mf = 0; mf < 2; ++mf) {
    float4 bv = *(const float4*)(bs + wci + mf * 16 + lhi * 4);
    float bb[4] = {bv.x, bv.y, bv.z, bv.w};
    if (which < 2) {
      ushort_t* ob = ((which == 0) ? theta_b : phi_b) + (size_t)b * Nn * CIn;
#pragma unroll
      for (int nf = 0; nf < 4; ++nf) {
        int n = n0 + nf * 16 + ln;
        unsigned lo = (unsigned)f2bf(acc[mf][nf][0] + bb[0]) |
                      ((unsigned)f2bf(acc[mf][nf][1] + bb[1]) << 16);
        unsigned hi = (unsigned)f2bf(acc[mf][nf][2] + bb[2]) |
                      ((unsigned)f2bf(acc[mf][nf][3] + bb[3]) << 16);
        ushort_t* base = ob + (size_t)n * CIn + wci + mf * 16 + lhi * 4;
        *(unsigned*)base = lo;
        *(unsigned*)(base + 2) = hi;
      }
    } else {
      ushort_t* ob = g_b + (size_t)b * CIn * Nn;
#pragma unroll
      for (int nf = 0; nf < 4; ++nf) {
#pragma unroll
        for (int r = 0; r < 4; ++r) {
          int ci = wci + mf * 16 + lhi * 4 + r;
          ob[(size_t)ci * Nn + n0 + nf * 16 + ln] = f2bf(acc[mf][nf][r] + bb[r]);
        }
      }
    }
  }
}

// ---------------- MFMA flash attention (bf16) ----------------
__global__ __launch_bounds__(256) void k_attn_mfma(
    const ushort_t* __restrict__ theta_b, const ushort_t* __restrict__ phi_b,
    const ushort_t* __restrict__ g_b, float* __restrict__ y) {
  __shared__ __align__(16) ushort_t lphi[64 * 128];
  __shared__ __align__(16) ushort_t lg[128 * 64];
  __shared__ __align__(16) ushort_t lP[4][16 * 64];

  const int tid = threadIdx.x;
  const int lane = tid & 63, w = tid >> 6;
  const int ln = lane & 15, lhi = lane >> 4;

  const int lid = blockIdx.x + 64 * blockIdx.y;
  const int xcd = lid & 7, slot = lid >> 3;
  const int b = xcd >> 1;
  const int n0 = ((xcd & 1) * 32 + slot) * 64;

  bfrag qf[4];
  {
    const ushort_t* thp =
        theta_b + ((size_t)(b * Nn + n0 + w * 16 + ln)) * CIn + 8 * lhi;
#pragma unroll
    for (int kb = 0; kb < 4; ++kb) qf[kb] = *(const bfrag*)(thp + kb * 32);
  }

  f32x4 yacc[8];
#pragma unroll
  for (int df = 0; df < 8; ++df) yacc[df] = (f32x4){0.f, 0.f, 0.f, 0.f};
  float mrow[4] = {-3e38f, -3e38f, -3e38f, -3e38f};
  float lrow[4] = {0.f, 0.f, 0.f, 0.f};

  const int pm_ = tid >> 4, pch = tid & 15;
  const int gd_ = tid >> 3, gch = tid & 7;
  const ushort_t* phiBase = phi_b + (size_t)b * Nn * CIn + (size_t)pm_ * CIn + pch * 8;
  const ushort_t* gBase   = g_b   + (size_t)b * CIn * Nn + (size_t)gd_ * Nn + gch * 8;
  uint4 rp[4], rg[4];
  int offp[4], offg[4];
#pragma unroll
  for (int it = 0; it < 4; ++it) {
    offp[it] = (((pm_ + it * 16) * 128 + pch * 8) * 2) ^ ((pm_ & 7) << 4);
    offg[it] = (((gd_ + it * 32) * 64 + gch * 8) * 2) ^ ((gd_ & 7) << 4);
  }
#pragma unroll
  for (int it = 0; it < 4; ++it) {
    rp[it] = *(const uint4*)(phiBase + (size_t)it * 16 * CIn);
    rg[it] = *(const uint4*)(gBase + (size_t)it * 32 * Nn);
  }

  ushort_t* lPw = lP[w];

  for (int t = 0; t < 64; ++t) {
    __syncthreads();
#pragma unroll
    for (int it = 0; it < 4; ++it) {
      *(uint4*)((char*)lphi + offp[it]) = rp[it];
      *(uint4*)((char*)lg + offg[it]) = rg[it];
    }
    if (t < 63) {
      const int m1 = (t + 1) * 64;
#pragma unroll
      for (int it = 0; it < 4; ++it) {
        rp[it] = *(const uint4*)(phiBase + (size_t)(m1 + it * 16) * CIn);
        rg[it] = *(const uint4*)(gBase + m1 + (size_t)it * 32 * Nn);
      }
    }
    __syncthreads();

    f32x4 sacc[4];
#pragma unroll
    for (int nf = 0; nf < 4; ++nf) sacc[nf] = (f32x4){0.f, 0.f, 0.f, 0.f};
    __builtin_amdgcn_s_setprio(1);
#pragma unroll
    for (int kb = 0; kb < 4; ++kb) {
#pragma unroll
      for (int nf = 0; nf < 4; ++nf) {
        int row = nf * 16 + ln;
        int off = ((row * 128 + kb * 32 + 8 * lhi) * 2) ^ ((ln & 7) << 4);
        bfrag pf = *(const bfrag*)((const char*)lphi + off);
        sacc[nf] = __builtin_amdgcn_mfma_f32_16x16x32_bf16(qf[kb], pf, sacc[nf], 0, 0, 0);
      }
    }
    __builtin_amdgcn_s_setprio(0);

    float aa[4], ps[4];
#pragma unroll
    for (int r = 0; r < 4; ++r) {
      float v = fmaxf(fmaxf(sacc[0][r], sacc[1][r]), fmaxf(sacc[2][r], sacc[3][r]));
      v = fmaxf(v, __shfl_xor(v, 1));
      v = fmaxf(v, __shfl_xor(v, 2));
      v = fmaxf(v, __shfl_xor(v, 4));
      v = fmaxf(v, __shfl_xor(v, 8));
      float nm = fmaxf(mrow[r], v);
      aa[r] = __expf(mrow[r] - nm);
      mrow[r] = nm;
      ps[r] = 0.f;
    }
#pragma unroll
    for (int nf = 0; nf < 4; ++nf) {
#pragma unroll
      for (int r = 0; r < 4; ++r) {
        float p = __expf(sacc[nf][r] - mrow[r]);
        ps[r] += p;
        int q = lhi * 4 + r;
        int off = ((q * 64 + nf * 16 + ln) * 2) ^ ((q & 7) << 4);
        *(ushort_t*)((char*)lPw + off) = f2bf(p);
      }
    }
#pragma unroll
    for (int r = 0; r < 4; ++r) {
      float v = ps[r];
      v += __shfl_xor(v, 1);
      v += __shfl_xor(v, 2);
      v += __shfl_xor(v, 4);
      v += __shfl_xor(v, 8);
      lrow[r] = lrow[r] * aa[r] + v;
    }
#pragma unroll
    for (int df = 0; df < 8; ++df)
#pragma unroll
      for (int r = 0; r < 4; ++r) yacc[df][r] *= aa[r];

    __builtin_amdgcn_s_setprio(1);
#pragma unroll
    for (int kb2 = 0; kb2 < 2; ++kb2) {
      int offa = ((ln * 64 + kb2 * 32 + 8 * lhi) * 2) ^ ((ln & 7) << 4);
      bfrag pa = *(const bfrag*)((const char*)lPw + offa);
#pragma unroll
      for (int df = 0; df < 8; ++df) {
        int d = df * 16 + ln;
        int offb = ((d * 64 + kb2 * 32 + 8 * lhi) * 2) ^ ((ln & 7) << 4);
        bfrag gbf = *(const bfrag*)((const char*)lg + offb);
        yacc[df] = __builtin_amdgcn_mfma_f32_16x16x32_bf16(pa, gbf, yacc[df], 0, 0, 0);
      }
    }
    __builtin_amdgcn_s_setprio(0);
  }

#pragma unroll
  for (int r = 0; r < 4; ++r) lrow[r] = 1.f / lrow[r];
  float* yp = y + (size_t)b * CIn * Nn + n0 + w * 16 + lhi * 4;
#pragma unroll
  for (int df = 0; df < 8; ++df)
#pragma unroll
    for (int r = 0; r < 4; ++r)
      yp[(size_t)(df * 16 + ln) * Nn + r] = yacc[df][r] * lrow[r];
}

// ---------------- final 1x1 via MFMA: wy[256][N] = ww[256][128] @ y[128][N] + wb ----------------
// grid (64 ntiles, 4 b), 512 thr / 8 waves; wave -> co w*32.
__global__ __launch_bounds__(512) void k_wconv_mfma(
    const float* __restrict__ y, const ushort_t* __restrict__ wwb,
    const float* __restrict__ wb, float* __restrict__ wy) {
  __shared__ __align__(16) ushort_t lyt[64 * 128];   // [n][ci], swz ^((n&7)<<4)
  const int tid = threadIdx.x;
  const int lane = tid & 63, w = tid >> 6;
  const int ln = lane & 15, lhi = lane >> 4;
  const int n0 = blockIdx.x * 64, b = blockIdx.y;
  const int wco = w * 32;

  for (int i = tid; i < 2048; i += 512) {
    int ci = i >> 4, n4 = (i & 15) * 4;
    float4 v = *(const float4*)(y + ((size_t)(b * CIn + ci)) * Nn + n0 + n4);
    float vv[4] = {v.x, v.y, v.z, v.w};
#pragma unroll
    for (int j = 0; j < 4; ++j) {
      int n = n4 + j;
      int off = ((n * 128 + ci) * 2) ^ ((n & 7) << 4);
      *(ushort_t*)((char*)lyt + off) = f2bf(vv[j]);
    }
  }
  __syncthreads();

  f32x4 acc[2][4];
#pragma unroll
  for (int mf = 0; mf < 2; ++mf)
#pragma unroll
    for (int nf = 0; nf < 4; ++nf) acc[mf][nf] = (f32x4){0.f, 0.f, 0.f, 0.f};

#pragma unroll
  for (int kb = 0; kb < 4; ++kb) {
    const ushort_t* ap = wwb + (size_t)(wco + ln) * CIn + kb * 32 + lhi * 8;
    bfrag af0 = *(const bfrag*)ap;
    bfrag af1 = *(const bfrag*)(ap + 16 * CIn);
    __builtin_amdgcn_s_setprio(1);
#pragma unroll
    for (int nf = 0; nf < 4; ++nf) {
      int n = nf * 16 + ln;
      int off = ((n * 128 + kb * 32 + lhi * 8) * 2) ^ ((n & 7) << 4);
      bfrag bf = *(const bfrag*)((const char*)lyt + off);
      acc[0][nf] = __builtin_amdgcn_mfma_f32_16x16x32_bf16(af0, bf, acc[0][nf], 0, 0, 0);
      acc[1][nf] = __builtin_amdgcn_mfma_f32_16x16x32_bf16(af1, bf, acc[1][nf], 0, 0, 0);
    }
    __builtin_amdgcn_s_setprio(0);
  }

#pragma unroll
  for (int mf = 0; mf < 2; ++mf) {
    float4 bv = *(const float4*)(wb + wco + mf * 16 + lhi * 4);
    float bb[4] = {bv.x, bv.y, bv.z, bv.w};
#pragma unroll
    for (int nf = 0; nf < 4; ++nf) {
#pragma unroll
      for (int r = 0; r < 4; ++r) {
        int co = wco + mf * 16 + lhi * 4 + r;
        wy[((size_t)(b * Cn + co)) * Nn + n0 + nf * 16 + ln] = acc[mf][nf][r] + bb[r];
      }
    }
  }
}

// ---------------- final: out = GN2(wy)*0.1 + xs ----------------
__global__ __launch_bounds__(256) void k_final(
    const float* __restrict__ wy, const float* __restrict__ stats,
    const float* __restrict__ g2w, const float* __restrict__ g2b,
    const float* __restrict__ xs, float* __restrict__ out) {
  size_t i = ((size_t)blockIdx.x * 256 + threadIdx.x) * 4;
  int c = (int)((i >> 12) & 255);
  int bg = (int)(i >> 20) * Gn + (c >> 5);
  float mean = stats[bg * 2], rstd = stats[bg * 2 + 1];
  float sc = g2w[c] * rstd * 0.1f;
  float sb = (g2b[c] - mean * rstd * g2w[c]) * 0.1f;
  float4 v = *(const float4*)(wy + i);
  float4 xv = *(const float4*)(xs + i);
  v.x = v.x * sc + sb + xv.x;
  v.y = v.y * sc + sb + xv.y;
  v.z = v.z * sc + sb + xv.z;
  v.w = v.w * sc + sb + xv.w;
  *(float4*)(out + i) = v;
}

extern "C" void kernel_launch(void* const* d_in, const int* in_sizes, int n_in,
                              void* d_out, int out_size, void* d_ws, size_t ws_size,
                              hipStream_t stream) {
  (void)in_sizes; (void)n_in; (void)out_size; (void)ws_size;
  const float* x   = (const float*)d_in[0];
  const float* sw  = (const float*)d_in[1];
  const float* sb  = (const float*)d_in[2];
  const float* g1w = (const float*)d_in[3];
  const float* g1b = (const float*)d_in[4];
  const float* gw  = (const float*)d_in[5];
  const float* gb  = (const float*)d_in[6];
  const float* thw = (const float*)d_in[7];
  const float* thb = (const float*)d_in[8];
  const float* phw = (const float*)d_in[9];
  const float* phb = (const float*)d_in[10];
  const float* ww  = (const float*)d_in[11];
  const float* wb  = (const float*)d_in[12];
  const float* g2w = (const float*)d_in[13];
  const float* g2b = (const float*)d_in[14];
  float* out = (float*)d_out;
  float* ws = (float*)d_ws;

  float*    xs_raw  = ws;                              // 4,194,304 f (reused as wy)
  float*    xs      = ws + 4194304;                    // 4,194,304 f
  float*    y_      = ws + 8388608;                    // 2,097,152 f  [B][Ci][N]
  float*    part    = ws + 10485760;                   // 1024 f
  float*    st1     = ws + 10486784;                   // 64 f
  float*    st2     = ws + 10486848;                   // 64 f
  ushort_t* theta_b = (ushort_t*)(ws + 10486912);      // 2,097,152 u16 [B][N][Ci]
  ushort_t* phi_b   = (ushort_t*)(ws + 11535488);      // 2,097,152 u16 [B][N][Ci]
  ushort_t* g_b     = (ushort_t*)(ws + 12584064);      // 2,097,152 u16 [B][Ci][N]
  ushort_t* xsT     = (ushort_t*)(ws + 13632640);      // 4,194,304 u16 [B][N][C]
  ushort_t* w9      = (ushort_t*)(ws + 15729792);      // 589,824 u16 [9][256][256]
  ushort_t* wp9     = (ushort_t*)(ws + 16024704);      // 98,304 u16 [3][128][256]
  ushort_t* wwb     = (ushort_t*)(ws + 16073856);      // 32,768 u16 [256][128]
  float*    wy      = xs_raw;

  k_prepack<<<2816, 256, 0, stream>>>(sw, thw, phw, gw, ww, w9, wp9, wwb);
  k_conv_mfma<<<dim3(Hn, Bn), 512, 0, stream>>>(x, w9, sb, xs_raw);
  k_gn_part<<<dim3(16, 8, 4), 256, 0, stream>>>(xs_raw, part);
  k_gn_final<<<1, 64, 0, stream>>>(part, st1);
  k_gn1_apply_t<<<dim3(64, 8, 4), 256, 0, stream>>>(xs_raw, st1, g1w, g1b, xs, xsT);
  k_proj_mfma<<<dim3(64, 3, 4), 256, 0, stream>>>(xsT, wp9, thb, phb, gb,
                                                  theta_b, phi_b, g_b);
  k_attn_mfma<<<dim3(64, 4), 256, 0, stream>>>(theta_b, phi_b, g_b, y_);
  k_wconv_mfma<<<dim3(64, 4), 512, 0, stream>>>(y_, wwb, wb, wy);
  k_gn_part<<<dim3(16, 8, 4), 256, 0, stream>>>(wy, part);
  k_gn_final<<<1, 64, 0, stream>>>(part, st2);
  k_final<<<4096, 256, 0, stream>>>(wy, st2, g2w, g2b, xs, out);
}

// Round 5
// 267.440 us; speedup vs baseline: 6.8768x; 1.2397x over previous
//
#include <hip/hip_runtime.h>
#include <math.h>

#define Bn 4
#define Cn 256
#define CIn 128
#define Hn 64
#define Wn 64
#define Nn 4096
#define Gn 8
#define CPGn 32
#define EPSc 1e-5f

typedef unsigned short ushort_t;
typedef short bfrag __attribute__((ext_vector_type(8)));       // 8 bf16 (4 VGPRs)
typedef float f32x4 __attribute__((ext_vector_type(4)));
typedef ushort_t u16x8 __attribute__((ext_vector_type(8)));

static __device__ __forceinline__ ushort_t f2bf(float f) {
  unsigned u = __float_as_uint(f);
  return (ushort_t)((u + 0x7FFFu + ((u >> 16) & 1u)) >> 16);   // RNE
}

// ---------------- weight prepack (fp32 -> bf16, rearranged) ----------------
__global__ __launch_bounds__(256) void k_prepack(
    const float* __restrict__ w3, const float* __restrict__ thw,
    const float* __restrict__ phw, const float* __restrict__ gww,
    const float* __restrict__ ww,
    ushort_t* __restrict__ w9, ushort_t* __restrict__ wp9,
    ushort_t* __restrict__ wwb) {
  int i = blockIdx.x * 256 + threadIdx.x;
  if (i < 589824) {
    float v = w3[i];
    int co = i / 2304, r = i % 2304, ci = r / 9, tap = r % 9;
    w9[tap * 65536 + co * 256 + ci] = f2bf(v);
  } else if (i < 688128) {
    int j = i - 589824;
    int which = j >> 15, r = j & 32767;
    const float* src = (which == 0) ? thw : (which == 1) ? phw : gww;
    wp9[j] = f2bf(src[r]);
  } else if (i < 720896) {
    int j = i - 688128;
    wwb[j] = f2bf(ww[j]);
  }
}

// ---------------- conv3x3 via implicit-GEMM MFMA ----------------
__global__ __launch_bounds__(512) void k_conv_mfma(
    const float* __restrict__ x, const ushort_t* __restrict__ w9,
    const float* __restrict__ b3, float* __restrict__ out) {
  __shared__ __align__(16) ushort_t lx[3 * 66 * 128];   // [dh][wp][ci], byte swz ^((wp&7)<<4)
  const int tid = threadIdx.x;
  const int lane = tid & 63, w = tid >> 6;
  const int ln = lane & 15, lhi = lane >> 4;
  const int h = blockIdx.x, b = blockIdx.y;
  const int wco = w * 32;

  f32x4 acc[2][4];
#pragma unroll
  for (int mf = 0; mf < 2; ++mf)
#pragma unroll
    for (int nf = 0; nf < 4; ++nf) acc[mf][nf] = (f32x4){0.f, 0.f, 0.f, 0.f};

  for (int cc = 0; cc < 2; ++cc) {
    __syncthreads();
    for (int i = tid; i < 768; i += 512) {
      int dh = i / 256, r = i % 256, wpz = (r >> 7) ? 65 : 0, ci = r & 127;
      int off = (((dh * 66 + wpz) * 128 + ci) * 2) ^ ((wpz & 7) << 4);
      *(ushort_t*)((char*)lx + off) = 0;
    }
    for (int i = tid; i < 6144; i += 512) {
      int dh = i >> 11, r = i & 2047, ci = r >> 4, w4 = (r & 15) * 4;
      int hh = h + dh - 1;
      float4 v = {0.f, 0.f, 0.f, 0.f};
      if (hh >= 0 && hh < Hn)
        v = *(const float4*)(x + (((size_t)(b * Cn + cc * 128 + ci)) * Hn + hh) * Wn + w4);
      float vv[4] = {v.x, v.y, v.z, v.w};
#pragma unroll
      for (int j = 0; j < 4; ++j) {
        int wp = 1 + w4 + j;
        int off = (((dh * 66 + wp) * 128 + ci) * 2) ^ ((wp & 7) << 4);
        *(ushort_t*)((char*)lx + off) = f2bf(vv[j]);
      }
    }
    __syncthreads();

#pragma unroll
    for (int tap = 0; tap < 9; ++tap) {
      const int dh = tap / 3, dw = tap % 3;
#pragma unroll
      for (int kb = 0; kb < 4; ++kb) {
        const ushort_t* ap = w9 + tap * 65536 + (size_t)(wco + ln) * 256 +
                             cc * 128 + kb * 32 + lhi * 8;
        bfrag af0 = *(const bfrag*)ap;
        bfrag af1 = *(const bfrag*)(ap + 16 * 256);
        __builtin_amdgcn_s_setprio(1);
#pragma unroll
        for (int nf = 0; nf < 4; ++nf) {
          int wp = nf * 16 + ln + dw;
          int off = (((dh * 66 + wp) * 128 + kb * 32 + lhi * 8) * 2) ^ ((wp & 7) << 4);
          bfrag bf = *(const bfrag*)((const char*)lx + off);
          acc[0][nf] = __builtin_amdgcn_mfma_f32_16x16x32_bf16(af0, bf, acc[0][nf], 0, 0, 0);
          acc[1][nf] = __builtin_amdgcn_mfma_f32_16x16x32_bf16(af1, bf, acc[1][nf], 0, 0, 0);
        }
        __builtin_amdgcn_s_setprio(0);
      }
    }
  }

#pragma unroll
  for (int mf = 0; mf < 2; ++mf) {
    float4 bv = *(const float4*)(b3 + wco + mf * 16 + lhi * 4);
    float bb[4] = {bv.x, bv.y, bv.z, bv.w};
#pragma unroll
    for (int nf = 0; nf < 4; ++nf) {
#pragma unroll
      for (int r = 0; r < 4; ++r) {
        int co = wco + mf * 16 + lhi * 4 + r;
        out[((size_t)(b * Cn + co)) * Nn + h * Wn + nf * 16 + ln] = acc[mf][nf][r] + bb[r];
      }
    }
  }
}

// ---------------- GroupNorm stats ----------------
__global__ __launch_bounds__(256) void k_gn_part(
    const float* __restrict__ xin, float* __restrict__ part) {
  const int s = blockIdx.x, g = blockIdx.y, b = blockIdx.z;
  const int t = threadIdx.x;
  const float* p = xin + ((size_t)b * Cn + g * CPGn) * Nn + s * 8192;
  float sum = 0.f, ssq = 0.f;
  for (int i = t * 4; i < 8192; i += 1024) {
    float4 v = *(const float4*)(p + i);
    sum += v.x + v.y + v.z + v.w;
    ssq += v.x * v.x + v.y * v.y + v.z * v.z + v.w * v.w;
  }
  __shared__ float r1[256], r2[256];
  r1[t] = sum; r2[t] = ssq;
  __syncthreads();
  for (int st = 128; st > 0; st >>= 1) {
    if (t < st) { r1[t] += r1[t + st]; r2[t] += r2[t + st]; }
    __syncthreads();
  }
  if (t == 0) {
    size_t idx = ((size_t)(b * Gn + g) * 16 + s) * 2;
    part[idx] = r1[0];
    part[idx + 1] = r2[0];
  }
}

__global__ void k_gn_final(const float* __restrict__ part, float* __restrict__ stats) {
  const int t = threadIdx.x;
  if (t < Bn * Gn) {
    float s = 0.f, ss = 0.f;
    for (int j = 0; j < 16; ++j) {
      s += part[(t * 16 + j) * 2];
      ss += part[(t * 16 + j) * 2 + 1];
    }
    const float inv = 1.f / (float)(CPGn * Nn);
    float mean = s * inv;
    float var = ss * inv - mean * mean;
    stats[t * 2] = mean;
    stats[t * 2 + 1] = rsqrtf(var + EPSc);
  }
}

// ---------------- GN1 apply + ReLU -> xs (fp32) and xsT (bf16 [B][N][C]) ----------------
__global__ __launch_bounds__(256) void k_gn1_apply_t(
    const float* __restrict__ xr, const float* __restrict__ stats,
    const float* __restrict__ gw, const float* __restrict__ gb,
    float* __restrict__ xs, ushort_t* __restrict__ xsT) {
  __shared__ ushort_t lt[32 * 64];
  const int t = threadIdx.x;
  const int n0 = blockIdx.x * 64, c0 = blockIdx.y * 32, b = blockIdx.z;
#pragma unroll
  for (int p = 0; p < 8; ++p) {
    int c = c0 + p * 4 + (t >> 6);
    int n = n0 + (t & 63);
    int bg = b * Gn + (c >> 5);
    float mean = stats[bg * 2], rstd = stats[bg * 2 + 1];
    float sc = gw[c] * rstd;
    float sb = gb[c] - mean * sc;
    size_t idx = ((size_t)(b * Cn + c)) * Nn + n;
    float val = fmaxf(xr[idx] * sc + sb, 0.f);
    xs[idx] = val;
    lt[(c - c0) * 64 + (t & 63)] = f2bf(val);
  }
  __syncthreads();
  {
    int n = t >> 2, cg = t & 3;
    u16x8 pk;
#pragma unroll
    for (int j = 0; j < 8; ++j) pk[j] = lt[(cg * 8 + j) * 64 + n];
    *(u16x8*)(xsT + ((size_t)(b * Nn + n0 + n)) * Cn + c0 + cg * 8) = pk;
  }
}

// ---------------- projections via MFMA ----------------
__global__ __launch_bounds__(256) void k_proj_mfma(
    const ushort_t* __restrict__ xsT, const ushort_t* __restrict__ wp9,
    const float* __restrict__ thb, const float* __restrict__ phb,
    const float* __restrict__ gbb,
    ushort_t* __restrict__ theta_b, ushort_t* __restrict__ phi_b,
    ushort_t* __restrict__ g_b) {
  __shared__ __align__(16) ushort_t lxs[64 * 256];   // [n][c], swz ^((n&7)<<4)
  const int tid = threadIdx.x;
  const int lane = tid & 63, w = tid >> 6;
  const int ln = lane & 15, lhi = lane >> 4;
  const int n0 = blockIdx.x * 64, which = blockIdx.y, b = blockIdx.z;
  const int wci = w * 32;

  for (int i = tid; i < 2048; i += 256) {
    int n = i >> 5, cchunk = (i & 31) * 8;
    uint4 v = *(const uint4*)(xsT + ((size_t)(b * Nn + n0 + n)) * Cn + cchunk);
    int off = ((n * 256 + cchunk) * 2) ^ ((n & 7) << 4);
    *(uint4*)((char*)lxs + off) = v;
  }
  __syncthreads();

  f32x4 acc[2][4];
#pragma unroll
  for (int mf = 0; mf < 2; ++mf)
#pragma unroll
    for (int nf = 0; nf < 4; ++nf) acc[mf][nf] = (f32x4){0.f, 0.f, 0.f, 0.f};

#pragma unroll
  for (int kb = 0; kb < 8; ++kb) {
    const ushort_t* ap = wp9 + which * 32768 + (size_t)(wci + ln) * 256 + kb * 32 + lhi * 8;
    bfrag af0 = *(const bfrag*)ap;
    bfrag af1 = *(const bfrag*)(ap + 16 * 256);
    __builtin_amdgcn_s_setprio(1);
#pragma unroll
    for (int nf = 0; nf < 4; ++nf) {
      int n = nf * 16 + ln;
      int off = ((n * 256 + kb * 32 + lhi * 8) * 2) ^ ((n & 7) << 4);
      bfrag bf = *(const bfrag*)((const char*)lxs + off);
      acc[0][nf] = __builtin_amdgcn_mfma_f32_16x16x32_bf16(af0, bf, acc[0][nf], 0, 0, 0);
      acc[1][nf] = __builtin_amdgcn_mfma_f32_16x16x32_bf16(af1, bf, acc[1][nf], 0, 0, 0);
    }
    __builtin_amdgcn_s_setprio(0);
  }

  const float* bs = (which == 0) ? thb : (which == 1) ? phb : gbb;
#pragma unroll
  for (int mf = 0; mf < 2; ++mf) {
    float4 bv = *(const float4*)(bs + wci + mf * 16 + lhi * 4);
    float bb[4] = {bv.x, bv.y, bv.z, bv.w};
    if (which < 2) {
      ushort_t* ob = ((which == 0) ? theta_b : phi_b) + (size_t)b * Nn * CIn;
#pragma unroll
      for (int nf = 0; nf < 4; ++nf) {
        int n = n0 + nf * 16 + ln;
        unsigned lo = (unsigned)f2bf(acc[mf][nf][0] + bb[0]) |
                      ((unsigned)f2bf(acc[mf][nf][1] + bb[1]) << 16);
        unsigned hi = (unsigned)f2bf(acc[mf][nf][2] + bb[2]) |
                      ((unsigned)f2bf(acc[mf][nf][3] + bb[3]) << 16);
        ushort_t* base = ob + (size_t)n * CIn + wci + mf * 16 + lhi * 4;
        *(unsigned*)base = lo;
        *(unsigned*)(base + 2) = hi;
      }
    } else {
      ushort_t* ob = g_b + (size_t)b * CIn * Nn;
#pragma unroll
      for (int nf = 0; nf < 4; ++nf) {
#pragma unroll
        for (int r = 0; r < 4; ++r) {
          int ci = wci + mf * 16 + lhi * 4 + r;
          ob[(size_t)ci * Nn + n0 + nf * 16 + ln] = f2bf(acc[mf][nf][r] + bb[r]);
        }
      }
    }
  }
}

// ---------------- MFMA flash attention, split-KV (S=4) ----------------
// 1024 blocks, 4 waves. Block handles 64 q-rows x 1024 kv; partials out.
__global__ __launch_bounds__(256) void k_attn_split(
    const ushort_t* __restrict__ theta_b, const ushort_t* __restrict__ phi_b,
    const ushort_t* __restrict__ g_b, ushort_t* __restrict__ ypart,
    float* __restrict__ mpart, float* __restrict__ lpart) {
  __shared__ __align__(16) ushort_t lphi[64 * 128];
  __shared__ __align__(16) ushort_t lg[128 * 64];
  __shared__ __align__(16) ushort_t lP[4][16 * 64];

  const int tid = threadIdx.x;
  const int lane = tid & 63, w = tid >> 6;
  const int ln = lane & 15, lhi = lane >> 4;

  // same (b, kv-slice) on same XCD for L2 reuse
  const int bid = blockIdx.x;
  const int xcd = bid & 7, idx = bid >> 3;       // idx 0..127
  const int pair = xcd * 2 + (idx >> 6);         // 0..15
  const int b = pair >> 2, s = pair & 3;
  const int n0 = (idx & 63) * 64;
  const int kv0 = s * 1024;

  bfrag qf[4];
  {
    const ushort_t* thp =
        theta_b + ((size_t)(b * Nn + n0 + w * 16 + ln)) * CIn + 8 * lhi;
#pragma unroll
    for (int kb = 0; kb < 4; ++kb) qf[kb] = *(const bfrag*)(thp + kb * 32);
  }

  f32x4 yacc[8];
#pragma unroll
  for (int df = 0; df < 8; ++df) yacc[df] = (f32x4){0.f, 0.f, 0.f, 0.f};
  float mrow[4] = {-3e38f, -3e38f, -3e38f, -3e38f};
  float lrow[4] = {0.f, 0.f, 0.f, 0.f};

  const int pm_ = tid >> 4, pch = tid & 15;
  const int gd_ = tid >> 3, gch = tid & 7;
  const ushort_t* phiBase =
      phi_b + (size_t)b * Nn * CIn + (size_t)(kv0 + pm_) * CIn + pch * 8;
  const ushort_t* gBase =
      g_b + (size_t)b * CIn * Nn + (size_t)gd_ * Nn + kv0 + gch * 8;
  uint4 rp[4], rg[4];
  int offp[4], offg[4];
#pragma unroll
  for (int it = 0; it < 4; ++it) {
    offp[it] = (((pm_ + it * 16) * 128 + pch * 8) * 2) ^ ((pm_ & 7) << 4);
    offg[it] = (((gd_ + it * 32) * 64 + gch * 8) * 2) ^ ((gd_ & 7) << 4);
  }
#pragma unroll
  for (int it = 0; it < 4; ++it) {
    rp[it] = *(const uint4*)(phiBase + (size_t)it * 16 * CIn);
    rg[it] = *(const uint4*)(gBase + (size_t)it * 32 * Nn);
  }

  ushort_t* lPw = lP[w];

  for (int t = 0; t < 16; ++t) {
    __syncthreads();
#pragma unroll
    for (int it = 0; it < 4; ++it) {
      *(uint4*)((char*)lphi + offp[it]) = rp[it];
      *(uint4*)((char*)lg + offg[it]) = rg[it];
    }
    if (t < 15) {
      const int m1 = (t + 1) * 64;
#pragma unroll
      for (int it = 0; it < 4; ++it) {
        rp[it] = *(const uint4*)(phiBase + (size_t)(m1 + it * 16) * CIn);
        rg[it] = *(const uint4*)(gBase + m1 + (size_t)it * 32 * Nn);
      }
    }
    __syncthreads();

    f32x4 sacc[4];
#pragma unroll
    for (int nf = 0; nf < 4; ++nf) sacc[nf] = (f32x4){0.f, 0.f, 0.f, 0.f};
    __builtin_amdgcn_s_setprio(1);
#pragma unroll
    for (int kb = 0; kb < 4; ++kb) {
#pragma unroll
      for (int nf = 0; nf < 4; ++nf) {
        int row = nf * 16 + ln;
        int off = ((row * 128 + kb * 32 + 8 * lhi) * 2) ^ ((ln & 7) << 4);
        bfrag pf = *(const bfrag*)((const char*)lphi + off);
        sacc[nf] = __builtin_amdgcn_mfma_f32_16x16x32_bf16(qf[kb], pf, sacc[nf], 0, 0, 0);
      }
    }
    __builtin_amdgcn_s_setprio(0);

    float aa[4], ps[4];
#pragma unroll
    for (int r = 0; r < 4; ++r) {
      float v = fmaxf(fmaxf(sacc[0][r], sacc[1][r]), fmaxf(sacc[2][r], sacc[3][r]));
      v = fmaxf(v, __shfl_xor(v, 1));
      v = fmaxf(v, __shfl_xor(v, 2));
      v = fmaxf(v, __shfl_xor(v, 4));
      v = fmaxf(v, __shfl_xor(v, 8));
      float nm = fmaxf(mrow[r], v);
      aa[r] = __expf(mrow[r] - nm);
      mrow[r] = nm;
      ps[r] = 0.f;
    }
#pragma unroll
    for (int nf = 0; nf < 4; ++nf) {
#pragma unroll
      for (int r = 0; r < 4; ++r) {
        float p = __expf(sacc[nf][r] - mrow[r]);
        ps[r] += p;
        int q = lhi * 4 + r;
        int off = ((q * 64 + nf * 16 + ln) * 2) ^ ((q & 7) << 4);
        *(ushort_t*)((char*)lPw + off) = f2bf(p);
      }
    }
#pragma unroll
    for (int r = 0; r < 4; ++r) {
      float v = ps[r];
      v += __shfl_xor(v, 1);
      v += __shfl_xor(v, 2);
      v += __shfl_xor(v, 4);
      v += __shfl_xor(v, 8);
      lrow[r] = lrow[r] * aa[r] + v;
    }
#pragma unroll
    for (int df = 0; df < 8; ++df)
#pragma unroll
      for (int r = 0; r < 4; ++r) yacc[df][r] *= aa[r];

    __builtin_amdgcn_s_setprio(1);
#pragma unroll
    for (int kb2 = 0; kb2 < 2; ++kb2) {
      int offa = ((ln * 64 + kb2 * 32 + 8 * lhi) * 2) ^ ((ln & 7) << 4);
      bfrag pa = *(const bfrag*)((const char*)lPw + offa);
#pragma unroll
      for (int df = 0; df < 8; ++df) {
        int d = df * 16 + ln;
        int offb = ((d * 64 + kb2 * 32 + 8 * lhi) * 2) ^ ((ln & 7) << 4);
        bfrag gbf = *(const bfrag*)((const char*)lg + offb);
        yacc[df] = __builtin_amdgcn_mfma_f32_16x16x32_bf16(pa, gbf, yacc[df], 0, 0, 0);
      }
    }
    __builtin_amdgcn_s_setprio(0);
  }

  // partials (unnormalized): ypart[(b*4+s)][q][d] bf16, m/l fp32
  ushort_t* yp =
      ypart + ((size_t)((b * 4 + s) * Nn + n0 + w * 16 + lhi * 4)) * CIn + ln;
#pragma unroll
  for (int df = 0; df < 8; ++df)
#pragma unroll
    for (int r = 0; r < 4; ++r)
      yp[(size_t)r * CIn + df * 16] = f2bf(yacc[df][r]);
  if (ln == 0) {
#pragma unroll
    for (int r = 0; r < 4; ++r) {
      size_t qi = (size_t)(b * 4 + s) * Nn + n0 + w * 16 + lhi * 4 + r;
      mpart[qi] = mrow[r];
      lpart[qi] = lrow[r];
    }
  }
}

// ---------------- split merge: yT[b][n][d] bf16 ----------------
__global__ __launch_bounds__(256) void k_merge(
    const ushort_t* __restrict__ ypart, const float* __restrict__ mpart,
    const float* __restrict__ lpart, ushort_t* __restrict__ yT) {
  const int t = threadIdx.x;
  const int n = blockIdx.x * 64 + (t >> 2);
  const int b = blockIdx.y;
  const int d0 = (t & 3) * 32;
  float m[4], l[4];
#pragma unroll
  for (int s = 0; s < 4; ++s) {
    m[s] = mpart[(size_t)(b * 4 + s) * Nn + n];
    l[s] = lpart[(size_t)(b * 4 + s) * Nn + n];
  }
  float M = fmaxf(fmaxf(m[0], m[1]), fmaxf(m[2], m[3]));
  float L = 0.f, sc[4];
#pragma unroll
  for (int s = 0; s < 4; ++s) { sc[s] = __expf(m[s] - M); L += sc[s] * l[s]; }
  float inv = 1.f / L;
  float acc[32];
#pragma unroll
  for (int k = 0; k < 32; ++k) acc[k] = 0.f;
#pragma unroll
  for (int s = 0; s < 4; ++s) {
    const ushort_t* yp = ypart + ((size_t)((b * 4 + s) * Nn + n)) * CIn + d0;
#pragma unroll
    for (int k = 0; k < 4; ++k) {
      u16x8 v = *(const u16x8*)(yp + k * 8);
#pragma unroll
      for (int j = 0; j < 8; ++j)
        acc[k * 8 + j] += sc[s] * __uint_as_float((unsigned)v[j] << 16);
    }
  }
  ushort_t* op = yT + ((size_t)(b * Nn + n)) * CIn + d0;
#pragma unroll
  for (int k = 0; k < 4; ++k) {
    u16x8 pk;
#pragma unroll
    for (int j = 0; j < 8; ++j) pk[j] = f2bf(acc[k * 8 + j] * inv);
    *(u16x8*)(op + k * 8) = pk;
  }
}

// ---------------- final 1x1 via MFMA: wy[256][N] = ww @ yT^T + wb ----------------
__global__ __launch_bounds__(512) void k_wconv_mfma(
    const ushort_t* __restrict__ yT, const ushort_t* __restrict__ wwb,
    const float* __restrict__ wb, float* __restrict__ wy) {
  __shared__ __align__(16) ushort_t lyt[64 * 128];   // [n][ci], swz ^((n&7)<<4)
  const int tid = threadIdx.x;
  const int lane = tid & 63, w = tid >> 6;
  const int ln = lane & 15, lhi = lane >> 4;
  const int n0 = blockIdx.x * 64, b = blockIdx.y;
  const int wco = w * 32;

  for (int i = tid; i < 1024; i += 512) {
    int n = i >> 4, ch = (i & 15) * 8;
    uint4 v = *(const uint4*)(yT + ((size_t)(b * Nn + n0 + n)) * CIn + ch);
    int off = ((n * 128 + ch) * 2) ^ ((n & 7) << 4);
    *(uint4*)((char*)lyt + off) = v;
  }
  __syncthreads();

  f32x4 acc[2][4];
#pragma unroll
  for (int mf = 0; mf < 2; ++mf)
#pragma unroll
    for (int nf = 0; nf < 4; ++nf) acc[mf][nf] = (f32x4){0.f, 0.f, 0.f, 0.f};

#pragma unroll
  for (int kb = 0; kb < 4; ++kb) {
    const ushort_t* ap = wwb + (size_t)(wco + ln) * CIn + kb * 32 + lhi * 8;
    bfrag af0 = *(const bfrag*)ap;
    bfrag af1 = *(const bfrag*)(ap + 16 * CIn);
    __builtin_amdgcn_s_setprio(1);
#pragma unroll
    for (int nf = 0; nf < 4; ++nf) {
      int n = nf * 16 + ln;
      int off = ((n * 128 + kb * 32 + lhi * 8) * 2) ^ ((n & 7) << 4);
      bfrag bf = *(const bfrag*)((const char*)lyt + off);
      acc[0][nf] = __builtin_amdgcn_mfma_f32_16x16x32_bf16(af0, bf, acc[0][nf], 0, 0, 0);
      acc[1][nf] = __builtin_amdgcn_mfma_f32_16x16x32_bf16(af1, bf, acc[1][nf], 0, 0, 0);
    }
    __builtin_amdgcn_s_setprio(0);
  }

#pragma unroll
  for (int mf = 0; mf < 2; ++mf) {
    float4 bv = *(const float4*)(wb + wco + mf * 16 + lhi * 4);
    float bb[4] = {bv.x, bv.y, bv.z, bv.w};
#pragma unroll
    for (int nf = 0; nf < 4; ++nf) {
#pragma unroll
      for (int r = 0; r < 4; ++r) {
        int co = wco + mf * 16 + lhi * 4 + r;
        wy[((size_t)(b * Cn + co)) * Nn + n0 + nf * 16 + ln] = acc[mf][nf][r] + bb[r];
      }
    }
  }
}

// ---------------- final: out = GN2(wy)*0.1 + xs ----------------
__global__ __launch_bounds__(256) void k_final(
    const float* __restrict__ wy, const float* __restrict__ stats,
    const float* __restrict__ g2w, const float* __restrict__ g2b,
    const float* __restrict__ xs, float* __restrict__ out) {
  size_t i = ((size_t)blockIdx.x * 256 + threadIdx.x) * 4;
  int c = (int)((i >> 12) & 255);
  int bg = (int)(i >> 20) * Gn + (c >> 5);
  float mean = stats[bg * 2], rstd = stats[bg * 2 + 1];
  float sc = g2w[c] * rstd * 0.1f;
  float sb = (g2b[c] - mean * rstd * g2w[c]) * 0.1f;
  float4 v = *(const float4*)(wy + i);
  float4 xv = *(const float4*)(xs + i);
  v.x = v.x * sc + sb + xv.x;
  v.y = v.y * sc + sb + xv.y;
  v.z = v.z * sc + sb + xv.z;
  v.w = v.w * sc + sb + xv.w;
  *(float4*)(out + i) = v;
}

extern "C" void kernel_launch(void* const* d_in, const int* in_sizes, int n_in,
                              void* d_out, int out_size, void* d_ws, size_t ws_size,
                              hipStream_t stream) {
  (void)in_sizes; (void)n_in; (void)out_size; (void)ws_size;
  const float* x   = (const float*)d_in[0];
  const float* sw  = (const float*)d_in[1];
  const float* sb  = (const float*)d_in[2];
  const float* g1w = (const float*)d_in[3];
  const float* g1b = (const float*)d_in[4];
  const float* gw  = (const float*)d_in[5];
  const float* gb  = (const float*)d_in[6];
  const float* thw = (const float*)d_in[7];
  const float* thb = (const float*)d_in[8];
  const float* phw = (const float*)d_in[9];
  const float* phb = (const float*)d_in[10];
  const float* ww  = (const float*)d_in[11];
  const float* wb  = (const float*)d_in[12];
  const float* g2w = (const float*)d_in[13];
  const float* g2b = (const float*)d_in[14];
  float* out = (float*)d_out;
  float* ws = (float*)d_ws;

  float*    xs_raw  = ws;                              // 4,194,304 f: conv out; then ypart; then wy
  float*    xs      = ws + 4194304;                    // 4,194,304 f
  ushort_t* yT      = (ushort_t*)(ws + 8388608);       // 4,194,304 u16 [B][N][Ci]
  float*    part    = ws + 10485760;                   // 1024 f
  float*    st1     = ws + 10486784;                   // 64 f
  float*    st2     = ws + 10486848;                   // 64 f
  ushort_t* theta_b = (ushort_t*)(ws + 10486912);      // 2,097,152 u16 [B][N][Ci]
  ushort_t* phi_b   = (ushort_t*)(ws + 11535488);      // 2,097,152 u16 [B][N][Ci]
  ushort_t* g_b     = (ushort_t*)(ws + 12584064);      // 2,097,152 u16 [B][Ci][N]
  ushort_t* xsT     = (ushort_t*)(ws + 13632640);      // 4,194,304 u16 [B][N][C]; then m/l part
  ushort_t* w9      = (ushort_t*)(ws + 15729792);      // 589,824 u16
  ushort_t* wp9     = (ushort_t*)(ws + 16024704);      // 98,304 u16
  ushort_t* wwb     = (ushort_t*)(ws + 16073856);      // 32,768 u16
  ushort_t* ypart   = (ushort_t*)xs_raw;               // 8,388,608 u16 [B*4][N][Ci] (alias)
  float*    mpart   = (float*)xsT;                     // 65,536 f (alias, dead xsT)
  float*    lpart   = ((float*)xsT) + 65536;           // 65,536 f
  float*    wy      = xs_raw;                          // alias (ypart dead after merge)

  k_prepack<<<2816, 256, 0, stream>>>(sw, thw, phw, gw, ww, w9, wp9, wwb);
  k_conv_mfma<<<dim3(Hn, Bn), 512, 0, stream>>>(x, w9, sb, xs_raw);
  k_gn_part<<<dim3(16, 8, 4), 256, 0, stream>>>(xs_raw, part);
  k_gn_final<<<1, 64, 0, stream>>>(part, st1);
  k_gn1_apply_t<<<dim3(64, 8, 4), 256, 0, stream>>>(xs_raw, st1, g1w, g1b, xs, xsT);
  k_proj_mfma<<<dim3(64, 3, 4), 256, 0, stream>>>(xsT, wp9, thb, phb, gb,
                                                  theta_b, phi_b, g_b);
  k_attn_split<<<1024, 256, 0, stream>>>(theta_b, phi_b, g_b, ypart, mpart, lpart);
  k_merge<<<dim3(64, 4), 256, 0, stream>>>(ypart, mpart, lpart, yT);
  k_wconv_mfma<<<dim3(64, 4), 512, 0, stream>>>(yT, wwb, wb, wy);
  k_gn_part<<<dim3(16, 8, 4), 256, 0, stream>>>(wy, part);
  k_gn_final<<<1, 64, 0, stream>>>(part, st2);
  k_final<<<4096, 256, 0, stream>>>(wy, st2, g2w, g2b, xs, out);
}